// Round 2
// baseline (7283.311 us; speedup 1.0000x reference)
//
#include <hip/hip_runtime.h>
#include <hip/hip_bf16.h>
#include <math.h>

// Problem constants
#define B_SZ 16
#define SEQ 2048
#define D_MODEL 512
#define D_INNER 1024
#define D_STATE 16
#define D_CONV 4
#define M_TOK (B_SZ * SEQ)   // 32768 token rows total

// ---------------------------------------------------------------------------
// Generic tiled f32 GEMM: C[M,N] = A[M,K] @ Bw[N,K]^T (+bias) (+add)
// flags: bit0 = clip A to [-10,10]; bit1 = clip add to [-10,10]
// 64x64 tile, BK=16, 256 threads, 4x4 accum per thread.
// ---------------------------------------------------------------------------
__global__ __launch_bounds__(256) void gemm_nt(
    const float* __restrict__ A, const float* __restrict__ Bw,
    float* __restrict__ C, int M, int N, int K,
    int lda, int ldb, int ldc,
    const float* __restrict__ bias,
    const float* __restrict__ add, int ldadd, int flags)
{
    __shared__ float As[16][65];
    __shared__ float Bs[16][65];
    const int bm = blockIdx.y * 64;
    const int bn = blockIdx.x * 64;
    const int tid = threadIdx.x;
    const int ty = tid >> 4;    // 0..15
    const int tx = tid & 15;    // 0..15

    float acc[4][4] = {};

    for (int k0 = 0; k0 < K; k0 += 16) {
        #pragma unroll
        for (int i = 0; i < 4; i++) {
            int r = ty + i * 16;           // row within tile
            int c = tx;                    // k within tile
            float v = A[(size_t)(bm + r) * lda + (k0 + c)];
            if (flags & 1) v = fminf(fmaxf(v, -10.f), 10.f);
            As[c][r] = v;
            Bs[c][r] = Bw[(size_t)(bn + r) * ldb + (k0 + c)];
        }
        __syncthreads();
        #pragma unroll
        for (int kk = 0; kk < 16; kk++) {
            float a[4], b[4];
            #pragma unroll
            for (int i = 0; i < 4; i++) a[i] = As[kk][ty * 4 + i];
            #pragma unroll
            for (int j = 0; j < 4; j++) b[j] = Bs[kk][tx * 4 + j];
            #pragma unroll
            for (int i = 0; i < 4; i++)
                #pragma unroll
                for (int j = 0; j < 4; j++)
                    acc[i][j] += a[i] * b[j];
        }
        __syncthreads();
    }

    #pragma unroll
    for (int i = 0; i < 4; i++) {
        int m = bm + ty * 4 + i;
        #pragma unroll
        for (int j = 0; j < 4; j++) {
            int n = bn + tx * 4 + j;
            float v = acc[i][j];
            if (bias) v += bias[n];
            if (add) {
                float a = add[(size_t)m * ldadd + n];
                if (flags & 2) a = fminf(fmaxf(a, -10.f), 10.f);
                v += a;
            }
            C[(size_t)m * ldc + n] = v;
        }
    }
}

// ---------------------------------------------------------------------------
// Depthwise causal conv (width 4) + bias + SiLU.
// x_p lives in xres[:, 0:1024] (row stride 2048). Output xc [rows,1024].
// rows are whole batches, so t = row & (SEQ-1) is the in-sequence position.
// ---------------------------------------------------------------------------
__global__ __launch_bounds__(256) void conv_silu(
    const float* __restrict__ xres, const float* __restrict__ cw,
    const float* __restrict__ cb, float* __restrict__ xc)
{
    int idx = blockIdx.x * blockDim.x + threadIdx.x;  // over rows*D_INNER
    int c = idx & (D_INNER - 1);
    int bt = idx >> 10;
    int t = bt & (SEQ - 1);

    float acc = cb[c];
    #pragma unroll
    for (int k = 0; k < D_CONV; k++) {
        int tt = t - (D_CONV - 1) + k;
        if (tt >= 0)
            acc += xres[(size_t)(bt - (D_CONV - 1) + k) * 2048 + c] * cw[c * D_CONV + k];
    }
    float sig = 1.f / (1.f + expf(-acc));
    xc[(size_t)bt * D_INNER + c] = acc * sig;
}

// ---------------------------------------------------------------------------
// Skinny GEMM: BC[rows,32] = xc[rows,1024] @ W_x[32,1024]^T
// ---------------------------------------------------------------------------
__global__ __launch_bounds__(256) void gemm_n32(
    const float* __restrict__ A, const float* __restrict__ Bw,
    float* __restrict__ C)
{
    int tid = blockIdx.x * blockDim.x + threadIdx.x;
    int n = tid & 31;
    int m = tid >> 5;
    const float4* a4 = (const float4*)(A + (size_t)m * D_INNER);
    const float4* b4 = (const float4*)(Bw + (size_t)n * D_INNER);
    float acc = 0.f;
    #pragma unroll 4
    for (int k = 0; k < D_INNER / 4; k++) {
        float4 a = a4[k], b = b4[k];
        acc += a.x * b.x + a.y * b.y + a.z * b.z + a.w * b.w;
    }
    C[(size_t)m * 32 + n] = acc;
}

// ---------------------------------------------------------------------------
// Selective scan. One thread per (b, d) channel; 16 states in registers.
// dt read from xres[:, 0:1024]; res from xres[:, 1024:2048]; u from xc.
// Output y = (scan + u*D) * silu(res) written in-place over dt slot.
// ---------------------------------------------------------------------------
#define TCH 64
__global__ __launch_bounds__(64) void scan_kernel(
    float* __restrict__ xres, const float* __restrict__ xc,
    const float* __restrict__ BC, const float* __restrict__ A_log,
    const float* __restrict__ Dvec)
{
    __shared__ float sBC[TCH][32];
    __shared__ float sdt[TCH][64];
    __shared__ float su[TCH][64];
    __shared__ float sres[TCH][64];

    const int b  = blockIdx.x >> 4;        // batch within chunk
    const int dg = blockIdx.x & 15;        // 16 channel groups of 64
    const int lane = threadIdx.x;
    const int d = dg * 64 + lane;

    float A[D_STATE];
    #pragma unroll
    for (int n = 0; n < D_STATE; n++) A[n] = A_log[n];
    const float Dp = Dvec[d];

    float st[D_STATE] = {};

    for (int t0 = 0; t0 < SEQ; t0 += TCH) {
        __syncthreads();
        const size_t base = (size_t)b * SEQ + t0;

        {
            const float4* bc4 = (const float4*)(BC + base * 32);
            float4* s4 = (float4*)&sBC[0][0];
            #pragma unroll
            for (int i = 0; i < (TCH * 32 / 4) / 64; i++)
                s4[i * 64 + lane] = bc4[i * 64 + lane];
        }
        for (int tt = 0; tt < TCH; tt++) {
            size_t ro = (base + tt) * 2048 + dg * 64 + lane;
            sdt[tt][lane]  = xres[ro];
            sres[tt][lane] = xres[ro + 1024];
            su[tt][lane]   = xc[(base + tt) * D_INNER + dg * 64 + lane];
        }
        __syncthreads();

        for (int tt = 0; tt < TCH; tt++) {
            float dtv = sdt[tt][lane];
            float u   = su[tt][lane];
            float du  = dtv * u;
            float y = 0.f;
            #pragma unroll
            for (int n = 0; n < D_STATE; n++) {
                float e = dtv * A[n];
                e = fminf(fmaxf(e, -5.f), 5.f);
                float dA = expf(e);
                st[n] = dA * st[n] + du * sBC[tt][n];
                y += st[n] * sBC[tt][16 + n];
            }
            float r = sres[tt][lane];
            float sig = 1.f / (1.f + expf(-r));
            float outv = (y + u * Dp) * (r * sig);
            xres[(base + tt) * 2048 + d] = outv;
        }
    }
}

// ---------------------------------------------------------------------------
// LayerNorm over last dim (512), eps 1e-5, in-place.
// ---------------------------------------------------------------------------
__global__ __launch_bounds__(128) void ln_kernel(
    float* __restrict__ out, const float* __restrict__ g,
    const float* __restrict__ bta)
{
    const int row = blockIdx.x;
    float* p = out + (size_t)row * D_MODEL;
    const int tid = threadIdx.x;

    float4 v = ((const float4*)p)[tid];
    float s1 = v.x + v.y + v.z + v.w;
    float s2 = v.x * v.x + v.y * v.y + v.z * v.z + v.w * v.w;
    #pragma unroll
    for (int off = 32; off > 0; off >>= 1) {
        s1 += __shfl_xor(s1, off);
        s2 += __shfl_xor(s2, off);
    }
    __shared__ float r1[2], r2[2];
    if ((tid & 63) == 0) { r1[tid >> 6] = s1; r2[tid >> 6] = s2; }
    __syncthreads();
    s1 = r1[0] + r1[1];
    s2 = r2[0] + r2[1];

    const float mu  = s1 * (1.f / D_MODEL);
    const float var = s2 * (1.f / D_MODEL) - mu * mu;
    const float rstd = rsqrtf(var + 1e-5f);

    float4 gg = ((const float4*)g)[tid];
    float4 bb = ((const float4*)bta)[tid];
    float4 o;
    o.x = (v.x - mu) * rstd * gg.x + bb.x;
    o.y = (v.y - mu) * rstd * gg.y + bb.y;
    o.z = (v.z - mu) * rstd * gg.z + bb.z;
    o.w = (v.w - mu) * rstd * gg.w + bb.w;
    ((float4*)p)[tid] = o;
}

// ---------------------------------------------------------------------------
// Chunked launcher: process CB batches at a time so f32 workspace fits ws_size.
// Per-batch ws need: 2048 rows * (2048 + 1024 + 32) floats * 4 B = 25,427,968 B.
// ---------------------------------------------------------------------------
extern "C" void kernel_launch(void* const* d_in, const int* in_sizes, int n_in,
                              void* d_out, int out_size, void* d_ws, size_t ws_size,
                              hipStream_t stream)
{
    const float* x      = (const float*)d_in[0];
    const float* W_in   = (const float*)d_in[1];
    const float* conv_w = (const float*)d_in[2];
    const float* conv_b = (const float*)d_in[3];
    const float* W_x    = (const float*)d_in[4];
    const float* W_dt   = (const float*)d_in[5];
    const float* b_dt   = (const float*)d_in[6];
    const float* A_log  = (const float*)d_in[7];
    const float* Dv     = (const float*)d_in[8];
    const float* W_out  = (const float*)d_in[9];
    const float* ln_g   = (const float*)d_in[10];
    const float* ln_b   = (const float*)d_in[11];
    float* out = (float*)d_out;

    // Pick largest power-of-two chunk (in batches) that fits the workspace.
    const size_t per_batch = (size_t)SEQ * (2048 + 1024 + 32) * sizeof(float);
    int cb = 16;
    while (cb > 1 && (size_t)cb * per_batch > ws_size) cb >>= 1;
    const int Mc = cb * SEQ;               // rows per chunk

    float* ws   = (float*)d_ws;
    float* xres = ws;                                  // [Mc, 2048]
    float* xc   = ws + (size_t)Mc * 2048;              // [Mc, 1024]
    float* BC   = xc + (size_t)Mc * D_INNER;           // [Mc, 32]

    for (int b0 = 0; b0 < B_SZ; b0 += cb) {
        const float* xk   = x   + (size_t)b0 * SEQ * D_MODEL;
        float*       outk = out + (size_t)b0 * SEQ * D_MODEL;

        // 1) xres = clip(x) @ W_in^T         [Mc,512]x[2048,512]^T
        {
            dim3 grid(2048 / 64, Mc / 64);
            gemm_nt<<<grid, 256, 0, stream>>>(xk, W_in, xres, Mc, 2048, D_MODEL,
                                              D_MODEL, D_MODEL, 2048,
                                              nullptr, nullptr, 0, /*clipA*/1);
        }
        // 2) xc = silu(depthwise_conv(x_p) + conv_b)
        conv_silu<<<((size_t)Mc * D_INNER) / 256, 256, 0, stream>>>(xres, conv_w, conv_b, xc);

        // 3) BC = xc @ W_x^T                 [Mc,1024]x[32,1024]^T
        gemm_n32<<<((size_t)Mc * 32) / 256, 256, 0, stream>>>(xc, W_x, BC);

        // 4) dt = xc @ W_dt^T + b_dt  -> xres[:, 0:1024] (ldc=2048)
        {
            dim3 grid(D_INNER / 64, Mc / 64);
            gemm_nt<<<grid, 256, 0, stream>>>(xc, W_dt, xres, Mc, D_INNER, D_INNER,
                                              D_INNER, D_INNER, 2048,
                                              b_dt, nullptr, 0, 0);
        }
        // 5) selective scan + u*D + silu(res) gate; y overwrites dt slot
        scan_kernel<<<cb * 16, 64, 0, stream>>>(xres, xc, BC, A_log, Dv);

        // 6) out = y @ W_out^T + clip(x)     [Mc,1024]x[512,1024]^T
        {
            dim3 grid(D_MODEL / 64, Mc / 64);
            gemm_nt<<<grid, 256, 0, stream>>>(xres, W_out, outk, Mc, D_MODEL, D_INNER,
                                              2048, D_INNER, D_MODEL,
                                              nullptr, xk, D_MODEL, /*clip add*/2);
        }
        // 7) LayerNorm in-place
        ln_kernel<<<Mc, 128, 0, stream>>>(outk, ln_g, ln_b);
    }
}

// Round 3
// 1825.562 us; speedup vs baseline: 3.9896x; 3.9896x over previous
//
#include <hip/hip_runtime.h>
#include <hip/hip_bf16.h>
#include <math.h>

#define B_SZ 16
#define SEQ 2048
#define D_MODEL 512
#define D_INNER 1024
#define D_STATE 16
#define D_CONV 4
#define NSEG 16
#define SEGLEN (SEQ / NSEG)   // 128

typedef __attribute__((ext_vector_type(8))) short short8;
typedef __attribute__((ext_vector_type(4))) float f32x4;
typedef const __attribute__((address_space(1))) void* gas_ptr;
typedef __attribute__((address_space(3))) void* las_ptr;

__device__ __forceinline__ float bf2f(unsigned int bits16) {
    union { unsigned int i; float f; } v; v.i = bits16 << 16; return v.f;
}
__device__ __forceinline__ unsigned short f2bf(float f) {
    union { float f; unsigned int i; } v; v.f = f;
    unsigned int r = v.i + 0x7FFFu + ((v.i >> 16) & 1u);
    return (unsigned short)(r >> 16);
}
__device__ __forceinline__ void async_g2l(const void* g, void* l) {
    __builtin_amdgcn_global_load_lds((gas_ptr)g, (las_ptr)l, 16, 0, 0);
}

// ---------------------------------------------------------------------------
// f32 -> bf16 cast (4 elements/thread), optional clip to [-10,10]
// ---------------------------------------------------------------------------
__global__ __launch_bounds__(256) void cast_bf16(
    const float4* __restrict__ in, ushort4* __restrict__ out, int n4, int do_clip)
{
    int i = blockIdx.x * 256 + threadIdx.x;
    if (i >= n4) return;
    float4 v = in[i];
    if (do_clip) {
        v.x = fminf(fmaxf(v.x, -10.f), 10.f);
        v.y = fminf(fmaxf(v.y, -10.f), 10.f);
        v.z = fminf(fmaxf(v.z, -10.f), 10.f);
        v.w = fminf(fmaxf(v.w, -10.f), 10.f);
    }
    ushort4 o;
    o.x = f2bf(v.x); o.y = f2bf(v.y); o.z = f2bf(v.z); o.w = f2bf(v.w);
    out[i] = o;
}

// ---------------------------------------------------------------------------
// bf16 MFMA NT-GEMM (m97 structure): C[M,N] = A[M,K] @ Bw[N,K]^T
// 128x128 tile, BK=32, 4 waves (2x2 of 64x64), 16x16x32 bf16 MFMA.
// f32 epilogue: +bias[n], +add[m,n] (optionally clipped to +-10).
// M,N multiples of 128; K multiple of 32.
// ---------------------------------------------------------------------------
__global__ __launch_bounds__(256) void gemm_bf16(
    const unsigned short* __restrict__ A, const unsigned short* __restrict__ Bw,
    float* __restrict__ C, int K, int ldc,
    const float* __restrict__ bias,
    const float* __restrict__ add, int ldadd, int clip_add)
{
    __shared__ unsigned short As[128][32];
    __shared__ unsigned short Bs[128][32];
    const int bm = blockIdx.y * 128;
    const int bn = blockIdx.x * 128;
    const int tid = threadIdx.x;
    const int wv = tid >> 6;          // wave 0..3
    const int l  = tid & 63;
    const int lr = l >> 2;            // 0..15 row-in-chunk for staging
    const int lc = l & 3;             // 16B column chunk for staging
    const int wm = (wv >> 1) * 64;    // wave tile origin
    const int wn = (wv & 1) * 64;
    const int r16 = l & 15;           // MFMA row/col lane index
    const int q   = l >> 4;           // MFMA quad

    f32x4 acc[4][4];
    #pragma unroll
    for (int i = 0; i < 4; i++)
        #pragma unroll
        for (int j = 0; j < 4; j++)
            acc[i][j] = (f32x4){0.f, 0.f, 0.f, 0.f};

    for (int k0 = 0; k0 < K; k0 += 32) {
        // Stage A-tile and B-tile (each 128 rows x 64 B) via global_load_lds.
        // Wave wv covers rows [wv*32, wv*32+32): 2 chunks of 16 rows (1024 B).
        #pragma unroll
        for (int p = 0; p < 2; p++) {
            int row = wv * 32 + p * 16 + lr;
            async_g2l((const char*)A + (((size_t)(bm + row)) * K + k0) * 2 + lc * 16,
                      (char*)&As[0][0] + (wv * 32 + p * 16) * 64);
            async_g2l((const char*)Bw + (((size_t)(bn + row)) * K + k0) * 2 + lc * 16,
                      (char*)&Bs[0][0] + (wv * 32 + p * 16) * 64);
        }
        __syncthreads();   // drains vmcnt (loads into LDS complete) + barrier

        short8 af[4], bf[4];
        #pragma unroll
        for (int i = 0; i < 4; i++) {
            af[i] = *(const short8*)&As[wm + i * 16 + r16][q * 8];
            bf[i] = *(const short8*)&Bs[wn + i * 16 + r16][q * 8];
        }
        #pragma unroll
        for (int i = 0; i < 4; i++)
            #pragma unroll
            for (int j = 0; j < 4; j++)
                acc[i][j] = __builtin_amdgcn_mfma_f32_16x16x32_bf16(
                    af[i], bf[j], acc[i][j], 0, 0, 0);
        __syncthreads();   // frags consumed; LDS free for next stage
    }

    #pragma unroll
    for (int i = 0; i < 4; i++) {
        #pragma unroll
        for (int rr = 0; rr < 4; rr++) {
            int m = bm + wm + i * 16 + q * 4 + rr;
            #pragma unroll
            for (int j = 0; j < 4; j++) {
                int n = bn + wn + j * 16 + r16;
                float v = acc[i][j][rr];
                if (bias) v += bias[n];
                if (add) {
                    float a = add[(size_t)m * ldadd + n];
                    if (clip_add) a = fminf(fmaxf(a, -10.f), 10.f);
                    v += a;
                }
                C[(size_t)m * ldc + n] = v;
            }
        }
    }
}

// ---------------------------------------------------------------------------
// Depthwise causal conv (width 4) + bias + SiLU; f32 in (stride 2048) -> bf16.
// ---------------------------------------------------------------------------
__global__ __launch_bounds__(256) void conv_silu(
    const float* __restrict__ xres, const float* __restrict__ cw,
    const float* __restrict__ cb, unsigned short* __restrict__ xc)
{
    int idx = blockIdx.x * 256 + threadIdx.x;
    int c = idx & (D_INNER - 1);
    int bt = idx >> 10;
    int t = bt & (SEQ - 1);

    float acc = cb[c];
    #pragma unroll
    for (int k = 0; k < D_CONV; k++) {
        int tt = t - (D_CONV - 1) + k;
        if (tt >= 0)
            acc += xres[(size_t)(bt - (D_CONV - 1) + k) * 2048 + c] * cw[c * D_CONV + k];
    }
    float sig = 1.f / (1.f + expf(-acc));
    xc[(size_t)bt * D_INNER + c] = f2bf(acc * sig);
}

// ---------------------------------------------------------------------------
// Skinny GEMM: BC[rows,32] = xc_bf[rows,1024] @ W_x_bf[32,1024]^T (f32 accum)
// ---------------------------------------------------------------------------
__global__ __launch_bounds__(256) void gemm_n32(
    const unsigned short* __restrict__ A, const unsigned short* __restrict__ Bw,
    float* __restrict__ C)
{
    int tid = blockIdx.x * 256 + threadIdx.x;
    int n = tid & 31;
    int m = tid >> 5;
    const uint4* a4 = (const uint4*)(A + (size_t)m * D_INNER);
    const uint4* b4 = (const uint4*)(Bw + (size_t)n * D_INNER);
    float acc = 0.f;
    #pragma unroll 2
    for (int k = 0; k < D_INNER / 8; k++) {
        uint4 a = a4[k], b = b4[k];
        acc += bf2f(a.x & 0xffff) * bf2f(b.x & 0xffff) + bf2f(a.x >> 16) * bf2f(b.x >> 16);
        acc += bf2f(a.y & 0xffff) * bf2f(b.y & 0xffff) + bf2f(a.y >> 16) * bf2f(b.y >> 16);
        acc += bf2f(a.z & 0xffff) * bf2f(b.z & 0xffff) + bf2f(a.z >> 16) * bf2f(b.z >> 16);
        acc += bf2f(a.w & 0xffff) * bf2f(b.w & 0xffff) + bf2f(a.w >> 16) * bf2f(b.w >> 16);
    }
    C[(size_t)m * 32 + n] = acc;
}

// ---------------------------------------------------------------------------
// Segmented selective scan, phase A: per (b, seg, d) run segment with st=0,
// record final local state and per-state log-decay sum.
// Layout stA/prA: [(b*NSEG+seg)*1024 + d]*16 + n
// ---------------------------------------------------------------------------
__global__ __launch_bounds__(64) void scan_phaseA(
    const float* __restrict__ xres, const float* __restrict__ BC,
    const unsigned short* __restrict__ xc, const float* __restrict__ A_log,
    float* __restrict__ stA, float* __restrict__ prA)
{
    const int bx = blockIdx.x;
    const int seg = bx & 15;
    const int dg  = (bx >> 4) & 15;
    const int b   = bx >> 8;
    const int lane = threadIdx.x;
    const int d = dg * 64 + lane;

    float Aa[16];
    #pragma unroll
    for (int n = 0; n < 4; n++) *(float4*)&Aa[n * 4] = ((const float4*)A_log)[n];

    const size_t rowbase = (size_t)b * SEQ + (size_t)seg * SEGLEN;
    const float* dtp = xres + rowbase * 2048 + dg * 64 + lane;
    const unsigned short* up = xc + rowbase * 1024 + dg * 64 + lane;
    const float* BCp = BC + rowbase * 32;

    float st[16] = {};
    float se[16] = {};

    for (int t = 0; t < SEGLEN; t++) {
        float dtv = dtp[(size_t)t * 2048];
        float u   = bf2f(up[(size_t)t * 1024]);
        float Bv[16];
        #pragma unroll
        for (int n = 0; n < 4; n++)
            *(float4*)&Bv[n * 4] = ((const float4*)(BCp + (size_t)t * 32))[n];
        float du = dtv * u;
        #pragma unroll
        for (int n = 0; n < 16; n++) {
            float e = fminf(fmaxf(dtv * Aa[n], -5.f), 5.f);
            se[n] += e;
            st[n] = expf(e) * st[n] + du * Bv[n];
        }
    }

    size_t o = (((size_t)b * NSEG + seg) * 1024 + d) * 16;
    #pragma unroll
    for (int n = 0; n < 16; n++) {
        stA[o + n] = st[n];
        prA[o + n] = expf(fminf(fmaxf(se[n], -80.f), 80.f));
    }
}

// ---------------------------------------------------------------------------
// Phase B: sequential combine over NSEG segments; parallel over (b,d,n).
// ---------------------------------------------------------------------------
__global__ __launch_bounds__(256) void scan_combine(
    const float* __restrict__ stA, const float* __restrict__ prA,
    float* __restrict__ stIn, int total)
{
    int idx = blockIdx.x * 256 + threadIdx.x;
    if (idx >= total) return;
    int dn = idx & 16383;           // d*16 + n
    int b  = idx >> 14;
    float prev = 0.f;
    for (int s = 0; s < NSEG; s++) {
        size_t o = ((size_t)b * NSEG + s) * 16384 + dn;
        stIn[o] = prev;
        prev = stA[o] + prA[o] * prev;
    }
}

// ---------------------------------------------------------------------------
// Phase C: re-run each segment with correct initial state; emit gated output
// y_bf = bf16((scan + u*D) * silu(res)).
// ---------------------------------------------------------------------------
__global__ __launch_bounds__(64) void scan_phaseC(
    const float* __restrict__ xres, const float* __restrict__ BC,
    const unsigned short* __restrict__ xc, const float* __restrict__ A_log,
    const float* __restrict__ Dvec, const float* __restrict__ stIn,
    unsigned short* __restrict__ y_bf)
{
    const int bx = blockIdx.x;
    const int seg = bx & 15;
    const int dg  = (bx >> 4) & 15;
    const int b   = bx >> 8;
    const int lane = threadIdx.x;
    const int d = dg * 64 + lane;

    float Aa[16];
    #pragma unroll
    for (int n = 0; n < 4; n++) *(float4*)&Aa[n * 4] = ((const float4*)A_log)[n];
    const float Dp = Dvec[d];

    const size_t rowbase = (size_t)b * SEQ + (size_t)seg * SEGLEN;
    const float* dtp  = xres + rowbase * 2048 + dg * 64 + lane;
    const float* resp = xres + rowbase * 2048 + 1024 + dg * 64 + lane;
    const unsigned short* up = xc + rowbase * 1024 + dg * 64 + lane;
    const float* BCp = BC + rowbase * 32;
    unsigned short* yp = y_bf + rowbase * 1024 + dg * 64 + lane;

    float st[16];
    size_t o = (((size_t)b * NSEG + seg) * 1024 + d) * 16;
    #pragma unroll
    for (int n = 0; n < 16; n++) st[n] = stIn[o + n];

    for (int t = 0; t < SEGLEN; t++) {
        float dtv = dtp[(size_t)t * 2048];
        float u   = bf2f(up[(size_t)t * 1024]);
        float Bv[16], Cv[16];
        #pragma unroll
        for (int n = 0; n < 4; n++) {
            *(float4*)&Bv[n * 4] = ((const float4*)(BCp + (size_t)t * 32))[n];
            *(float4*)&Cv[n * 4] = ((const float4*)(BCp + (size_t)t * 32))[n + 4];
        }
        float du = dtv * u;
        float y = 0.f;
        #pragma unroll
        for (int n = 0; n < 16; n++) {
            float e = fminf(fmaxf(dtv * Aa[n], -5.f), 5.f);
            st[n] = expf(e) * st[n] + du * Bv[n];
            y += st[n] * Cv[n];
        }
        float r = resp[(size_t)t * 2048];
        float sig = 1.f / (1.f + expf(-r));
        float outv = (y + u * Dp) * (r * sig);
        yp[(size_t)t * 1024] = f2bf(outv);
    }
}

// ---------------------------------------------------------------------------
// LayerNorm over last dim (512), eps 1e-5, in-place.
// ---------------------------------------------------------------------------
__global__ __launch_bounds__(128) void ln_kernel(
    float* __restrict__ out, const float* __restrict__ g,
    const float* __restrict__ bta)
{
    const int row = blockIdx.x;
    float* p = out + (size_t)row * D_MODEL;
    const int tid = threadIdx.x;

    float4 v = ((const float4*)p)[tid];
    float s1 = v.x + v.y + v.z + v.w;
    float s2 = v.x * v.x + v.y * v.y + v.z * v.z + v.w * v.w;
    #pragma unroll
    for (int off = 32; off > 0; off >>= 1) {
        s1 += __shfl_xor(s1, off);
        s2 += __shfl_xor(s2, off);
    }
    __shared__ float r1[2], r2[2];
    if ((tid & 63) == 0) { r1[tid >> 6] = s1; r2[tid >> 6] = s2; }
    __syncthreads();
    s1 = r1[0] + r1[1];
    s2 = r2[0] + r2[1];

    const float mu  = s1 * (1.f / D_MODEL);
    const float var = s2 * (1.f / D_MODEL) - mu * mu;
    const float rstd = rsqrtf(var + 1e-5f);

    float4 gg = ((const float4*)g)[tid];
    float4 bb = ((const float4*)bta)[tid];
    float4 o;
    o.x = (v.x - mu) * rstd * gg.x + bb.x;
    o.y = (v.y - mu) * rstd * gg.y + bb.y;
    o.z = (v.z - mu) * rstd * gg.z + bb.z;
    o.w = (v.w - mu) * rstd * gg.w + bb.w;
    ((float4*)p)[tid] = o;
}

// ---------------------------------------------------------------------------
extern "C" void kernel_launch(void* const* d_in, const int* in_sizes, int n_in,
                              void* d_out, int out_size, void* d_ws, size_t ws_size,
                              hipStream_t stream)
{
    const float* x      = (const float*)d_in[0];
    const float* W_in   = (const float*)d_in[1];
    const float* conv_w = (const float*)d_in[2];
    const float* conv_b = (const float*)d_in[3];
    const float* W_x    = (const float*)d_in[4];
    const float* W_dt   = (const float*)d_in[5];
    const float* b_dt   = (const float*)d_in[6];
    const float* A_log  = (const float*)d_in[7];
    const float* Dv     = (const float*)d_in[8];
    const float* W_out  = (const float*)d_in[9];
    const float* ln_g   = (const float*)d_in[10];
    const float* ln_b   = (const float*)d_in[11];
    float* out = (float*)d_out;

    // ---- workspace layout ----
    // fixed: bf16 weights
    const size_t szWin  = (size_t)2048 * 512;      // elements
    const size_t szWdt  = (size_t)1024 * 1024;
    const size_t szWout = (size_t)512 * 1024;
    const size_t szWx   = (size_t)32 * 1024;
    char* p = (char*)d_ws;
    unsigned short* Wib  = (unsigned short*)p; p += szWin * 2;
    unsigned short* Wdtb = (unsigned short*)p; p += szWdt * 2;
    unsigned short* Wob  = (unsigned short*)p; p += szWout * 2;
    unsigned short* Wxb  = (unsigned short*)p; p += szWx * 2;
    const size_t fixed_bytes = (size_t)(p - (char*)d_ws);

    // per-batch activation bytes
    const size_t per_batch =
        (size_t)SEQ * 2048 * 4      // xres f32
      + (size_t)SEQ * 512 * 2       // x_bf
      + (size_t)SEQ * 1024 * 2      // xc_bf
      + (size_t)SEQ * 1024 * 2      // y_bf
      + (size_t)SEQ * 32 * 4        // BC
      + (size_t)3 * NSEG * 1024 * 16 * 4;  // stA, prA, stIn
    int cb = 16;
    while (cb > 1 && fixed_bytes + (size_t)cb * per_batch > ws_size) cb >>= 1;
    const int Mc = cb * SEQ;

    float*          xres  = (float*)p;            p += (size_t)Mc * 2048 * 4;
    unsigned short* x_bf  = (unsigned short*)p;   p += (size_t)Mc * 512 * 2;
    unsigned short* xc_bf = (unsigned short*)p;   p += (size_t)Mc * 1024 * 2;
    unsigned short* y_bf  = (unsigned short*)p;   p += (size_t)Mc * 1024 * 2;
    float*          BCb   = (float*)p;            p += (size_t)Mc * 32 * 4;
    float*          stA   = (float*)p;            p += (size_t)cb * NSEG * 16384 * 4;
    float*          prA   = (float*)p;            p += (size_t)cb * NSEG * 16384 * 4;
    float*          stIn  = (float*)p;

    // ---- cast weights to bf16 (once per call) ----
    cast_bf16<<<(int)(szWin / 4 + 255) / 256, 256, 0, stream>>>((const float4*)W_in,  (ushort4*)Wib,  (int)(szWin / 4), 0);
    cast_bf16<<<(int)(szWdt / 4 + 255) / 256, 256, 0, stream>>>((const float4*)W_dt,  (ushort4*)Wdtb, (int)(szWdt / 4), 0);
    cast_bf16<<<(int)(szWout / 4 + 255) / 256, 256, 0, stream>>>((const float4*)W_out, (ushort4*)Wob, (int)(szWout / 4), 0);
    cast_bf16<<<(int)(szWx / 4 + 255) / 256, 256, 0, stream>>>((const float4*)W_x,   (ushort4*)Wxb,  (int)(szWx / 4), 0);

    for (int b0 = 0; b0 < B_SZ; b0 += cb) {
        const float* xk   = x   + (size_t)b0 * SEQ * D_MODEL;
        float*       outk = out + (size_t)b0 * SEQ * D_MODEL;

        // 0) x -> bf16 with clip
        cast_bf16<<<(Mc * 512 / 4) / 256, 256, 0, stream>>>(
            (const float4*)xk, (ushort4*)x_bf, Mc * 512 / 4, 1);

        // 1) xres = clip(x) @ W_in^T   [Mc,512]x[2048,512]^T -> f32 [Mc,2048]
        gemm_bf16<<<dim3(2048 / 128, Mc / 128), 256, 0, stream>>>(
            x_bf, Wib, xres, 512, 2048, nullptr, nullptr, 0, 0);

        // 2) xc_bf = silu(conv(x_p) + conv_b)
        conv_silu<<<((size_t)Mc * D_INNER) / 256, 256, 0, stream>>>(xres, conv_w, conv_b, xc_bf);

        // 3) BC = xc @ W_x^T  -> f32 [Mc,32]
        gemm_n32<<<((size_t)Mc * 32) / 256, 256, 0, stream>>>(xc_bf, Wxb, BCb);

        // 4) dt = xc @ W_dt^T + b_dt -> xres[:,0:1024] (ldc=2048)
        gemm_bf16<<<dim3(1024 / 128, Mc / 128), 256, 0, stream>>>(
            xc_bf, Wdtb, xres, 1024, 2048, b_dt, nullptr, 0, 0);

        // 5) segmented scan
        scan_phaseA<<<cb * 256, 64, 0, stream>>>(xres, BCb, xc_bf, A_log, stA, prA);
        scan_combine<<<cb * 64, 256, 0, stream>>>(stA, prA, stIn, cb * 16384);
        scan_phaseC<<<cb * 256, 64, 0, stream>>>(xres, BCb, xc_bf, A_log, Dv, stIn, y_bf);

        // 6) out = y @ W_out^T + clip(x)   [Mc,1024]x[512,1024]^T -> [Mc,512]
        gemm_bf16<<<dim3(512 / 128, Mc / 128), 256, 0, stream>>>(
            y_bf, Wob, outk, 1024, 512, nullptr, xk, 512, 1);

        // 7) LayerNorm in-place
        ln_kernel<<<Mc, 128, 0, stream>>>(outk, ln_g, ln_b);
    }
}

// Round 4
// 1259.771 us; speedup vs baseline: 5.7815x; 1.4491x over previous
//
#include <hip/hip_runtime.h>
#include <hip/hip_bf16.h>
#include <math.h>

#define B_SZ 16
#define SEQ 2048
#define D_MODEL 512
#define D_INNER 1024
#define D_STATE 16
#define D_CONV 4
#define NSEG 32
#define SEGLEN (SEQ / NSEG)   // 64
#define LOG2E 1.44269504f

typedef __attribute__((ext_vector_type(8))) short short8;
typedef __attribute__((ext_vector_type(4))) float f32x4;
typedef const __attribute__((address_space(1))) void* gas_ptr;
typedef __attribute__((address_space(3))) void* las_ptr;

__device__ __forceinline__ float bf2f(unsigned int bits16) {
    union { unsigned int i; float f; } v; v.i = bits16 << 16; return v.f;
}
__device__ __forceinline__ unsigned short f2bf(float f) {
    union { float f; unsigned int i; } v; v.f = f;
    unsigned int r = v.i + 0x7FFFu + ((v.i >> 16) & 1u);
    return (unsigned short)(r >> 16);
}
__device__ __forceinline__ void async_g2l(const void* g, void* l) {
    __builtin_amdgcn_global_load_lds((gas_ptr)g, (las_ptr)l, 16, 0, 0);
}
__device__ __forceinline__ float fast_exp2(float x) { return __builtin_amdgcn_exp2f(x); }
__device__ __forceinline__ float fast_rcp(float x)  { return __builtin_amdgcn_rcpf(x); }
__device__ __forceinline__ float silu(float x) {
    return x * fast_rcp(1.f + fast_exp2(-x * LOG2E));
}

// ---------------------------------------------------------------------------
// f32 -> bf16 cast (4 elements/thread), optional clip to [-10,10]
// ---------------------------------------------------------------------------
__global__ __launch_bounds__(256) void cast_bf16(
    const float4* __restrict__ in, ushort4* __restrict__ out, int n4, int do_clip)
{
    int i = blockIdx.x * 256 + threadIdx.x;
    if (i >= n4) return;
    float4 v = in[i];
    if (do_clip) {
        v.x = fminf(fmaxf(v.x, -10.f), 10.f);
        v.y = fminf(fmaxf(v.y, -10.f), 10.f);
        v.z = fminf(fmaxf(v.z, -10.f), 10.f);
        v.w = fminf(fmaxf(v.w, -10.f), 10.f);
    }
    ushort4 o;
    o.x = f2bf(v.x); o.y = f2bf(v.y); o.z = f2bf(v.z); o.w = f2bf(v.w);
    out[i] = o;
}

// ---------------------------------------------------------------------------
// bf16 MFMA NT-GEMM (m97 structure): C[M,N] = A[M,K] @ Bw[N,K]^T
// 128x128 tile, BK=32, 4 waves (2x2 of 64x64), 16x16x32 bf16 MFMA.
// f32 epilogue: +bias[n], +add[m,n] (optionally clipped to +-10).
// ---------------------------------------------------------------------------
__global__ __launch_bounds__(256) void gemm_bf16(
    const unsigned short* __restrict__ A, const unsigned short* __restrict__ Bw,
    float* __restrict__ C, int K, int ldc,
    const float* __restrict__ bias,
    const float* __restrict__ add, int ldadd, int clip_add)
{
    __shared__ unsigned short As[128][32];
    __shared__ unsigned short Bs[128][32];
    const int bm = blockIdx.y * 128;
    const int bn = blockIdx.x * 128;
    const int tid = threadIdx.x;
    const int wv = tid >> 6;
    const int l  = tid & 63;
    const int lr = l >> 2;
    const int lc = l & 3;
    const int wm = (wv >> 1) * 64;
    const int wn = (wv & 1) * 64;
    const int r16 = l & 15;
    const int q   = l >> 4;

    f32x4 acc[4][4];
    #pragma unroll
    for (int i = 0; i < 4; i++)
        #pragma unroll
        for (int j = 0; j < 4; j++)
            acc[i][j] = (f32x4){0.f, 0.f, 0.f, 0.f};

    for (int k0 = 0; k0 < K; k0 += 32) {
        #pragma unroll
        for (int p = 0; p < 2; p++) {
            int row = wv * 32 + p * 16 + lr;
            async_g2l((const char*)A + (((size_t)(bm + row)) * K + k0) * 2 + lc * 16,
                      (char*)&As[0][0] + (wv * 32 + p * 16) * 64);
            async_g2l((const char*)Bw + (((size_t)(bn + row)) * K + k0) * 2 + lc * 16,
                      (char*)&Bs[0][0] + (wv * 32 + p * 16) * 64);
        }
        __syncthreads();

        short8 af[4], bf[4];
        #pragma unroll
        for (int i = 0; i < 4; i++) {
            af[i] = *(const short8*)&As[wm + i * 16 + r16][q * 8];
            bf[i] = *(const short8*)&Bs[wn + i * 16 + r16][q * 8];
        }
        #pragma unroll
        for (int i = 0; i < 4; i++)
            #pragma unroll
            for (int j = 0; j < 4; j++)
                acc[i][j] = __builtin_amdgcn_mfma_f32_16x16x32_bf16(
                    af[i], bf[j], acc[i][j], 0, 0, 0);
        __syncthreads();
    }

    #pragma unroll
    for (int i = 0; i < 4; i++) {
        #pragma unroll
        for (int rr = 0; rr < 4; rr++) {
            int m = bm + wm + i * 16 + q * 4 + rr;
            #pragma unroll
            for (int j = 0; j < 4; j++) {
                int n = bn + wn + j * 16 + r16;
                float v = acc[i][j][rr];
                if (bias) v += bias[n];
                if (add) {
                    float a = add[(size_t)m * ldadd + n];
                    if (clip_add) a = fminf(fmaxf(a, -10.f), 10.f);
                    v += a;
                }
                C[(size_t)m * ldc + n] = v;
            }
        }
    }
}

// ---------------------------------------------------------------------------
// Depthwise causal conv (width 4) + bias + SiLU; 4 channels/thread (float4).
// x_p in xres[:, 0:1024] (row stride 2048, f32) -> xc bf16 [rows,1024].
// ---------------------------------------------------------------------------
__global__ __launch_bounds__(256) void conv_silu(
    const float* __restrict__ xres, const float* __restrict__ cw,
    const float* __restrict__ cb, unsigned short* __restrict__ xc)
{
    int idx = blockIdx.x * 256 + threadIdx.x;   // rows * 256 threads
    int c4 = (idx & 255) << 2;                  // channel group of 4
    int bt = idx >> 8;
    int t  = bt & (SEQ - 1);

    float4 acc = *(const float4*)(cb + c4);
    float4 w0 = *(const float4*)(cw + (c4 + 0) * 4);
    float4 w1 = *(const float4*)(cw + (c4 + 1) * 4);
    float4 w2 = *(const float4*)(cw + (c4 + 2) * 4);
    float4 w3 = *(const float4*)(cw + (c4 + 3) * 4);

    #pragma unroll
    for (int k = 0; k < D_CONV; k++) {
        int tt = t - (D_CONV - 1) + k;
        if (tt >= 0) {
            float4 xv = *(const float4*)(xres + (size_t)(bt - (D_CONV - 1) + k) * 2048 + c4);
            acc.x += xv.x * ((const float*)&w0)[k];
            acc.y += xv.y * ((const float*)&w1)[k];
            acc.z += xv.z * ((const float*)&w2)[k];
            acc.w += xv.w * ((const float*)&w3)[k];
        }
    }
    ushort4 o;
    o.x = f2bf(silu(acc.x));
    o.y = f2bf(silu(acc.y));
    o.z = f2bf(silu(acc.z));
    o.w = f2bf(silu(acc.w));
    *(ushort4*)(xc + (size_t)bt * 1024 + c4) = o;
}

// ---------------------------------------------------------------------------
// Skinny GEMM: BC[rows,32] = xc_bf[rows,1024] @ W_x_bf[32,1024]^T (f32 accum)
// ---------------------------------------------------------------------------
__global__ __launch_bounds__(256) void gemm_n32(
    const unsigned short* __restrict__ A, const unsigned short* __restrict__ Bw,
    float* __restrict__ C)
{
    int tid = blockIdx.x * 256 + threadIdx.x;
    int n = tid & 31;
    int m = tid >> 5;
    const uint4* a4 = (const uint4*)(A + (size_t)m * D_INNER);
    const uint4* b4 = (const uint4*)(Bw + (size_t)n * D_INNER);
    float acc = 0.f;
    #pragma unroll 2
    for (int k = 0; k < D_INNER / 8; k++) {
        uint4 a = a4[k], b = b4[k];
        acc += bf2f(a.x & 0xffff) * bf2f(b.x & 0xffff) + bf2f(a.x >> 16) * bf2f(b.x >> 16);
        acc += bf2f(a.y & 0xffff) * bf2f(b.y & 0xffff) + bf2f(a.y >> 16) * bf2f(b.y >> 16);
        acc += bf2f(a.z & 0xffff) * bf2f(b.z & 0xffff) + bf2f(a.z >> 16) * bf2f(b.z >> 16);
        acc += bf2f(a.w & 0xffff) * bf2f(b.w & 0xffff) + bf2f(a.w >> 16) * bf2f(b.w >> 16);
    }
    C[(size_t)m * 32 + n] = acc;
}

// ---------------------------------------------------------------------------
// Segmented scan phase A: per (b, seg, d), run segment with st=0; record
// final local state and segment decay product (via exp2 of summed log2-decay).
// A2[n] = A_log[n]*log2e folded in; clip +-5 becomes +-5*log2e.
// Last segment's partials are never consumed -> skip.
// ---------------------------------------------------------------------------
__global__ __launch_bounds__(64) void scan_phaseA(
    const float* __restrict__ xres, const float* __restrict__ BC,
    const unsigned short* __restrict__ xc, const float* __restrict__ A_log,
    float* __restrict__ stA, float* __restrict__ prA)
{
    const int bx = blockIdx.x;
    const int seg = bx & (NSEG - 1);
    const int dg  = (bx >> 5) & 15;
    const int b   = bx >> 9;
    if (seg == NSEG - 1) return;
    const int lane = threadIdx.x;
    const int d = dg * 64 + lane;
    const float CL = 5.f * LOG2E;

    float A2[16];
    #pragma unroll
    for (int n = 0; n < 16; n++) A2[n] = A_log[n] * LOG2E;

    const size_t rowbase = (size_t)b * SEQ + (size_t)seg * SEGLEN;
    const float* dtp = xres + rowbase * 2048 + d;
    const unsigned short* up = xc + rowbase * 1024 + d;
    const float* BCp = BC + rowbase * 32;

    float st[16] = {};
    float se[16] = {};

    for (int t = 0; t < SEGLEN; t++) {
        float dtv = dtp[(size_t)t * 2048];
        float u   = bf2f(up[(size_t)t * 1024]);
        float Bv[16];
        #pragma unroll
        for (int n = 0; n < 4; n++)
            *(float4*)&Bv[n * 4] = ((const float4*)(BCp + (size_t)t * 32))[n];
        float du = dtv * u;
        #pragma unroll
        for (int n = 0; n < 16; n++) {
            float e = fminf(fmaxf(dtv * A2[n], -CL), CL);
            se[n] += e;
            st[n] = fast_exp2(e) * st[n] + du * Bv[n];
        }
    }

    size_t o = (((size_t)b * NSEG + seg) * 1024 + d) * 16;
    #pragma unroll
    for (int n = 0; n < 16; n++) {
        stA[o + n] = st[n];
        prA[o + n] = fast_exp2(fminf(fmaxf(se[n], -115.41f), 115.41f));
    }
}

// ---------------------------------------------------------------------------
// Phase B: sequential combine over NSEG segments; stIn written IN PLACE over
// stA (read-before-write makes aliasing safe). Parallel over (b,d,n).
// ---------------------------------------------------------------------------
__global__ __launch_bounds__(256) void scan_combine(
    float* __restrict__ stA, const float* __restrict__ prA, int total)
{
    int idx = blockIdx.x * 256 + threadIdx.x;
    if (idx >= total) return;
    int dn = idx & 16383;           // d*16 + n
    int b  = idx >> 14;
    float prev = 0.f;
    for (int s = 0; s < NSEG; s++) {
        size_t o = ((size_t)b * NSEG + s) * 16384 + dn;
        float a = stA[o], pr = prA[o];
        stA[o] = prev;              // becomes stIn[seg]
        prev = a + pr * prev;       // garbage for s==NSEG-1, discarded
    }
}

// ---------------------------------------------------------------------------
// Phase C: re-run each segment with correct initial state (stIn aliased in
// stA); emit gated output y_bf = bf16((scan + u*D) * silu(res)).
// ---------------------------------------------------------------------------
__global__ __launch_bounds__(64) void scan_phaseC(
    const float* __restrict__ xres, const float* __restrict__ BC,
    const unsigned short* __restrict__ xc, const float* __restrict__ A_log,
    const float* __restrict__ Dvec, const float* __restrict__ stIn,
    unsigned short* __restrict__ y_bf)
{
    const int bx = blockIdx.x;
    const int seg = bx & (NSEG - 1);
    const int dg  = (bx >> 5) & 15;
    const int b   = bx >> 9;
    const int lane = threadIdx.x;
    const int d = dg * 64 + lane;
    const float CL = 5.f * LOG2E;

    float A2[16];
    #pragma unroll
    for (int n = 0; n < 16; n++) A2[n] = A_log[n] * LOG2E;
    const float Dp = Dvec[d];

    const size_t rowbase = (size_t)b * SEQ + (size_t)seg * SEGLEN;
    const float* dtp  = xres + rowbase * 2048 + d;
    const float* resp = xres + rowbase * 2048 + 1024 + d;
    const unsigned short* up = xc + rowbase * 1024 + d;
    const float* BCp = BC + rowbase * 32;
    unsigned short* yp = y_bf + rowbase * 1024 + d;

    float st[16];
    size_t o = (((size_t)b * NSEG + seg) * 1024 + d) * 16;
    #pragma unroll
    for (int n = 0; n < 16; n++) st[n] = stIn[o + n];

    for (int t = 0; t < SEGLEN; t++) {
        float dtv = dtp[(size_t)t * 2048];
        float u   = bf2f(up[(size_t)t * 1024]);
        float Bv[16], Cv[16];
        #pragma unroll
        for (int n = 0; n < 4; n++) {
            *(float4*)&Bv[n * 4] = ((const float4*)(BCp + (size_t)t * 32))[n];
            *(float4*)&Cv[n * 4] = ((const float4*)(BCp + (size_t)t * 32))[n + 4];
        }
        float du = dtv * u;
        float y = 0.f;
        #pragma unroll
        for (int n = 0; n < 16; n++) {
            float e = fminf(fmaxf(dtv * A2[n], -CL), CL);
            st[n] = fast_exp2(e) * st[n] + du * Bv[n];
            y += st[n] * Cv[n];
        }
        float r = resp[(size_t)t * 2048];
        float outv = (y + u * Dp) * silu(r);
        yp[(size_t)t * 1024] = f2bf(outv);
    }
}

// ---------------------------------------------------------------------------
// LayerNorm over last dim (512), eps 1e-5, in-place.
// ---------------------------------------------------------------------------
__global__ __launch_bounds__(128) void ln_kernel(
    float* __restrict__ out, const float* __restrict__ g,
    const float* __restrict__ bta)
{
    const int row = blockIdx.x;
    float* p = out + (size_t)row * D_MODEL;
    const int tid = threadIdx.x;

    float4 v = ((const float4*)p)[tid];
    float s1 = v.x + v.y + v.z + v.w;
    float s2 = v.x * v.x + v.y * v.y + v.z * v.z + v.w * v.w;
    #pragma unroll
    for (int off = 32; off > 0; off >>= 1) {
        s1 += __shfl_xor(s1, off);
        s2 += __shfl_xor(s2, off);
    }
    __shared__ float r1[2], r2[2];
    if ((tid & 63) == 0) { r1[tid >> 6] = s1; r2[tid >> 6] = s2; }
    __syncthreads();
    s1 = r1[0] + r1[1];
    s2 = r2[0] + r2[1];

    const float mu  = s1 * (1.f / D_MODEL);
    const float var = s2 * (1.f / D_MODEL) - mu * mu;
    const float rstd = rsqrtf(var + 1e-5f);

    float4 gg = ((const float4*)g)[tid];
    float4 bb = ((const float4*)bta)[tid];
    float4 o;
    o.x = (v.x - mu) * rstd * gg.x + bb.x;
    o.y = (v.y - mu) * rstd * gg.y + bb.y;
    o.z = (v.z - mu) * rstd * gg.z + bb.z;
    o.w = (v.w - mu) * rstd * gg.w + bb.w;
    ((float4*)p)[tid] = o;
}

// ---------------------------------------------------------------------------
extern "C" void kernel_launch(void* const* d_in, const int* in_sizes, int n_in,
                              void* d_out, int out_size, void* d_ws, size_t ws_size,
                              hipStream_t stream)
{
    const float* x      = (const float*)d_in[0];
    const float* W_in   = (const float*)d_in[1];
    const float* conv_w = (const float*)d_in[2];
    const float* conv_b = (const float*)d_in[3];
    const float* W_x    = (const float*)d_in[4];
    const float* W_dt   = (const float*)d_in[5];
    const float* b_dt   = (const float*)d_in[6];
    const float* A_log  = (const float*)d_in[7];
    const float* Dv     = (const float*)d_in[8];
    const float* W_out  = (const float*)d_in[9];
    const float* ln_g   = (const float*)d_in[10];
    const float* ln_b   = (const float*)d_in[11];
    float* out = (float*)d_out;

    // ---- fixed workspace: bf16 weights ----
    const size_t szWin  = (size_t)2048 * 512;
    const size_t szWdt  = (size_t)1024 * 1024;
    const size_t szWout = (size_t)512 * 1024;
    const size_t szWx   = (size_t)32 * 1024;
    char* p = (char*)d_ws;
    unsigned short* Wib  = (unsigned short*)p; p += szWin * 2;
    unsigned short* Wdtb = (unsigned short*)p; p += szWdt * 2;
    unsigned short* Wob  = (unsigned short*)p; p += szWout * 2;
    unsigned short* Wxb  = (unsigned short*)p; p += szWx * 2;
    const size_t fixed_bytes = (size_t)(p - (char*)d_ws);

    // per-batch activation bytes (x_bf aliased into y_bf; stIn aliased in stA)
    const size_t per_batch =
        (size_t)SEQ * 2048 * 4                  // xres f32 (x_p/dt | res)
      + (size_t)SEQ * 1024 * 2                  // ybuf bf16 (also x_bf)
      + (size_t)SEQ * 1024 * 2                  // xc_bf
      + (size_t)SEQ * 32 * 4                    // BC f32
      + (size_t)2 * NSEG * 1024 * 16 * 4;       // stA, prA
    int cb = 16;
    while (cb > 1 && fixed_bytes + (size_t)cb * per_batch > ws_size) cb >>= 1;
    const int Mc = cb * SEQ;

    float*          xres  = (float*)p;          p += (size_t)Mc * 2048 * 4;
    unsigned short* ybuf  = (unsigned short*)p; p += (size_t)Mc * 1024 * 2;
    unsigned short* x_bf  = ybuf;               // dead before ybuf is written
    unsigned short* xc_bf = (unsigned short*)p; p += (size_t)Mc * 1024 * 2;
    float*          BCb   = (float*)p;          p += (size_t)Mc * 32 * 4;
    float*          stA   = (float*)p;          p += (size_t)cb * NSEG * 16384 * 4;
    float*          prA   = (float*)p;

    // ---- cast weights to bf16 (every call; ~10 us) ----
    cast_bf16<<<(int)(szWin / 4 + 255) / 256, 256, 0, stream>>>((const float4*)W_in,  (ushort4*)Wib,  (int)(szWin / 4), 0);
    cast_bf16<<<(int)(szWdt / 4 + 255) / 256, 256, 0, stream>>>((const float4*)W_dt,  (ushort4*)Wdtb, (int)(szWdt / 4), 0);
    cast_bf16<<<(int)(szWout / 4 + 255) / 256, 256, 0, stream>>>((const float4*)W_out, (ushort4*)Wob, (int)(szWout / 4), 0);
    cast_bf16<<<(int)(szWx / 4 + 255) / 256, 256, 0, stream>>>((const float4*)W_x,   (ushort4*)Wxb,  (int)(szWx / 4), 0);

    for (int b0 = 0; b0 < B_SZ; b0 += cb) {
        const float* xk   = x   + (size_t)b0 * SEQ * D_MODEL;
        float*       outk = out + (size_t)b0 * SEQ * D_MODEL;

        // 0) x -> bf16 with clip (into ybuf-aliased region)
        cast_bf16<<<(Mc * 512 / 4) / 256, 256, 0, stream>>>(
            (const float4*)xk, (ushort4*)x_bf, Mc * 512 / 4, 1);

        // 1) xres = clip(x) @ W_in^T   -> f32 [Mc,2048]
        gemm_bf16<<<dim3(2048 / 128, Mc / 128), 256, 0, stream>>>(
            x_bf, Wib, xres, 512, 2048, nullptr, nullptr, 0, 0);

        // 2) xc_bf = silu(conv(x_p) + conv_b)
        conv_silu<<<Mc, 256, 0, stream>>>(xres, conv_w, conv_b, xc_bf);

        // 3) BC = xc @ W_x^T  -> f32 [Mc,32]
        gemm_n32<<<((size_t)Mc * 32) / 256, 256, 0, stream>>>(xc_bf, Wxb, BCb);

        // 4) dt = xc @ W_dt^T + b_dt -> xres[:,0:1024] (ldc=2048)
        gemm_bf16<<<dim3(1024 / 128, Mc / 128), 256, 0, stream>>>(
            xc_bf, Wdtb, xres, 1024, 2048, b_dt, nullptr, 0, 0);

        // 5) segmented scan (A: partials; B: combine in place; C: emit y)
        scan_phaseA<<<cb * NSEG * 16, 64, 0, stream>>>(xres, BCb, xc_bf, A_log, stA, prA);
        scan_combine<<<(cb * 16384 + 255) / 256, 256, 0, stream>>>(stA, prA, cb * 16384);
        scan_phaseC<<<cb * NSEG * 16, 64, 0, stream>>>(xres, BCb, xc_bf, A_log, Dv, stA, ybuf);

        // 6) out = y @ W_out^T + clip(x)   -> [Mc,512]
        gemm_bf16<<<dim3(512 / 128, Mc / 128), 256, 0, stream>>>(
            ybuf, Wob, outk, 1024, 512, nullptr, xk, 512, 1);

        // 7) LayerNorm in-place
        ln_kernel<<<Mc, 128, 0, stream>>>(outk, ln_g, ln_b);
    }
}

// Round 5
// 1012.837 us; speedup vs baseline: 7.1910x; 1.2438x over previous
//
#include <hip/hip_runtime.h>
#include <hip/hip_bf16.h>
#include <math.h>

#define B_SZ 16
#define SEQ 2048
#define D_MODEL 512
#define D_INNER 1024
#define D_STATE 16
#define D_CONV 4
#define NSEG 32
#define SEGLEN (SEQ / NSEG)   // 64
#define LOG2E 1.44269504f

typedef __attribute__((ext_vector_type(8))) short short8;
typedef __attribute__((ext_vector_type(4))) float f32x4;
typedef const __attribute__((address_space(1))) void* gas_ptr;
typedef __attribute__((address_space(3))) void* las_ptr;

__device__ __forceinline__ float bf2f(unsigned int bits16) {
    union { unsigned int i; float f; } v; v.i = bits16 << 16; return v.f;
}
__device__ __forceinline__ unsigned short f2bf(float f) {
    union { float f; unsigned int i; } v; v.f = f;
    unsigned int r = v.i + 0x7FFFu + ((v.i >> 16) & 1u);
    return (unsigned short)(r >> 16);
}
__device__ __forceinline__ void async_g2l(const void* g, void* l) {
    __builtin_amdgcn_global_load_lds((gas_ptr)g, (las_ptr)l, 16, 0, 0);
}
__device__ __forceinline__ float fast_exp2(float x) { return __builtin_amdgcn_exp2f(x); }
__device__ __forceinline__ float fast_rcp(float x)  { return __builtin_amdgcn_rcpf(x); }
__device__ __forceinline__ float clamp3(float x, float lo, float hi) {
    return __builtin_amdgcn_fmed3f(x, lo, hi);
}
__device__ __forceinline__ float silu(float x) {
    return x * fast_rcp(1.f + fast_exp2(-x * LOG2E));
}

// ---------------------------------------------------------------------------
// f32 -> bf16 cast (4 elements/thread), optional clip to [-10,10]
// ---------------------------------------------------------------------------
__global__ __launch_bounds__(256) void cast_bf16(
    const float4* __restrict__ in, ushort4* __restrict__ out, int n4, int do_clip)
{
    int i = blockIdx.x * 256 + threadIdx.x;
    if (i >= n4) return;
    float4 v = in[i];
    if (do_clip) {
        v.x = clamp3(v.x, -10.f, 10.f);
        v.y = clamp3(v.y, -10.f, 10.f);
        v.z = clamp3(v.z, -10.f, 10.f);
        v.w = clamp3(v.w, -10.f, 10.f);
    }
    ushort4 o;
    o.x = f2bf(v.x); o.y = f2bf(v.y); o.z = f2bf(v.z); o.w = f2bf(v.w);
    out[i] = o;
}

// ---------------------------------------------------------------------------
// bf16 MFMA NT-GEMM (m97 structure): C[M,N] = A[M,K] @ Bw[N,K]^T
// 128x128 tile, BK=32, 4 waves (2x2 of 64x64), 16x16x32 bf16 MFMA.
// f32 epilogue: +bias[n], +add[m,n] (optionally clipped to +-10).
// ---------------------------------------------------------------------------
__global__ __launch_bounds__(256) void gemm_bf16(
    const unsigned short* __restrict__ A, const unsigned short* __restrict__ Bw,
    float* __restrict__ C, int K, int ldc,
    const float* __restrict__ bias,
    const float* __restrict__ add, int ldadd, int clip_add)
{
    __shared__ unsigned short As[128][32];
    __shared__ unsigned short Bs[128][32];
    const int bm = blockIdx.y * 128;
    const int bn = blockIdx.x * 128;
    const int tid = threadIdx.x;
    const int wv = tid >> 6;
    const int l  = tid & 63;
    const int lr = l >> 2;
    const int lc = l & 3;
    const int wm = (wv >> 1) * 64;
    const int wn = (wv & 1) * 64;
    const int r16 = l & 15;
    const int q   = l >> 4;

    f32x4 acc[4][4];
    #pragma unroll
    for (int i = 0; i < 4; i++)
        #pragma unroll
        for (int j = 0; j < 4; j++)
            acc[i][j] = (f32x4){0.f, 0.f, 0.f, 0.f};

    for (int k0 = 0; k0 < K; k0 += 32) {
        #pragma unroll
        for (int p = 0; p < 2; p++) {
            int row = wv * 32 + p * 16 + lr;
            async_g2l((const char*)A + (((size_t)(bm + row)) * K + k0) * 2 + lc * 16,
                      (char*)&As[0][0] + (wv * 32 + p * 16) * 64);
            async_g2l((const char*)Bw + (((size_t)(bn + row)) * K + k0) * 2 + lc * 16,
                      (char*)&Bs[0][0] + (wv * 32 + p * 16) * 64);
        }
        __syncthreads();

        short8 af[4], bf[4];
        #pragma unroll
        for (int i = 0; i < 4; i++) {
            af[i] = *(const short8*)&As[wm + i * 16 + r16][q * 8];
            bf[i] = *(const short8*)&Bs[wn + i * 16 + r16][q * 8];
        }
        #pragma unroll
        for (int i = 0; i < 4; i++)
            #pragma unroll
            for (int j = 0; j < 4; j++)
                acc[i][j] = __builtin_amdgcn_mfma_f32_16x16x32_bf16(
                    af[i], bf[j], acc[i][j], 0, 0, 0);
        __syncthreads();
    }

    #pragma unroll
    for (int i = 0; i < 4; i++) {
        #pragma unroll
        for (int rr = 0; rr < 4; rr++) {
            int m = bm + wm + i * 16 + q * 4 + rr;
            #pragma unroll
            for (int j = 0; j < 4; j++) {
                int n = bn + wn + j * 16 + r16;
                float v = acc[i][j][rr];
                if (bias) v += bias[n];
                if (add) {
                    float a = add[(size_t)m * ldadd + n];
                    if (clip_add) a = clamp3(a, -10.f, 10.f);
                    v += a;
                }
                C[(size_t)m * ldc + n] = v;
            }
        }
    }
}

// ---------------------------------------------------------------------------
// Skinny MFMA GEMM: BC[rows,32] = xc_bf[rows,1024] @ W_x_bf[32,1024]^T.
// One wave per 16 output rows; no LDS, no barriers. A-frag loads are 16 rows
// x 64 B contiguous per K-step (64B-segment coalesced); W_x (64 KB) is
// L1/L2-resident across all blocks. 2 MFMAs per K-step of 32.
// ---------------------------------------------------------------------------
__global__ __launch_bounds__(256) void gemm_bc(
    const unsigned short* __restrict__ A, const unsigned short* __restrict__ Bw,
    float* __restrict__ C)
{
    const int tid = threadIdx.x;
    const int wv  = tid >> 6;
    const int l   = tid & 63;
    const int r16 = l & 15;
    const int q   = l >> 4;
    const int row0 = blockIdx.x * 64 + wv * 16;

    const unsigned short* ap  = A  + (size_t)(row0 + r16) * 1024 + q * 8;
    const unsigned short* bp0 = Bw + (size_t)r16 * 1024 + q * 8;
    const unsigned short* bp1 = Bw + (size_t)(16 + r16) * 1024 + q * 8;

    f32x4 acc0 = {0.f, 0.f, 0.f, 0.f}, acc1 = {0.f, 0.f, 0.f, 0.f};
    #pragma unroll 4
    for (int k = 0; k < 1024; k += 32) {
        short8 af = *(const short8*)(ap + k);
        short8 b0 = *(const short8*)(bp0 + k);
        short8 b1 = *(const short8*)(bp1 + k);
        acc0 = __builtin_amdgcn_mfma_f32_16x16x32_bf16(af, b0, acc0, 0, 0, 0);
        acc1 = __builtin_amdgcn_mfma_f32_16x16x32_bf16(af, b1, acc1, 0, 0, 0);
    }
    #pragma unroll
    for (int rr = 0; rr < 4; rr++) {
        int m = row0 + q * 4 + rr;
        C[(size_t)m * 32 + r16]      = acc0[rr];
        C[(size_t)m * 32 + 16 + r16] = acc1[rr];
    }
}

// ---------------------------------------------------------------------------
// Depthwise causal conv (width 4) + bias + SiLU; 4 channels/thread (float4).
// x_p in xres[:, 0:1024] (row stride 2048, f32) -> xc bf16 [rows,1024].
// ---------------------------------------------------------------------------
__global__ __launch_bounds__(256) void conv_silu(
    const float* __restrict__ xres, const float* __restrict__ cw,
    const float* __restrict__ cb, unsigned short* __restrict__ xc)
{
    int idx = blockIdx.x * 256 + threadIdx.x;   // rows * 256 threads
    int c4 = (idx & 255) << 2;                  // channel group of 4
    int bt = idx >> 8;
    int t  = bt & (SEQ - 1);

    float4 acc = *(const float4*)(cb + c4);
    float4 w0 = *(const float4*)(cw + (c4 + 0) * 4);
    float4 w1 = *(const float4*)(cw + (c4 + 1) * 4);
    float4 w2 = *(const float4*)(cw + (c4 + 2) * 4);
    float4 w3 = *(const float4*)(cw + (c4 + 3) * 4);

    #pragma unroll
    for (int k = 0; k < D_CONV; k++) {
        int tt = t - (D_CONV - 1) + k;
        if (tt >= 0) {
            float4 xv = *(const float4*)(xres + (size_t)(bt - (D_CONV - 1) + k) * 2048 + c4);
            acc.x += xv.x * ((const float*)&w0)[k];
            acc.y += xv.y * ((const float*)&w1)[k];
            acc.z += xv.z * ((const float*)&w2)[k];
            acc.w += xv.w * ((const float*)&w3)[k];
        }
    }
    ushort4 o;
    o.x = f2bf(silu(acc.x));
    o.y = f2bf(silu(acc.y));
    o.z = f2bf(silu(acc.z));
    o.w = f2bf(silu(acc.w));
    *(ushort4*)(xc + (size_t)bt * 1024 + c4) = o;
}

// ---------------------------------------------------------------------------
// Segmented scan phase A: per (b, seg, d), run segment with st=0; record
// final local state and segment decay product (via exp2 of summed log2-decay).
// A2[n] = A_log[n]*log2e folded in; clip +-5 becomes +-5*log2e.
// ---------------------------------------------------------------------------
__global__ __launch_bounds__(64) void scan_phaseA(
    const float* __restrict__ xres, const float* __restrict__ BC,
    const unsigned short* __restrict__ xc, const float* __restrict__ A_log,
    float* __restrict__ stA, float* __restrict__ prA)
{
    const int bx = blockIdx.x;
    const int seg = bx & (NSEG - 1);
    const int dg  = (bx >> 5) & 15;
    const int b   = bx >> 9;
    if (seg == NSEG - 1) return;
    const int lane = threadIdx.x;
    const int d = dg * 64 + lane;
    const float CL = 5.f * LOG2E;

    float A2[16];
    #pragma unroll
    for (int n = 0; n < 16; n++) A2[n] = A_log[n] * LOG2E;

    const size_t rowbase = (size_t)b * SEQ + (size_t)seg * SEGLEN;
    const float* dtp = xres + rowbase * 2048 + d;
    const unsigned short* up = xc + rowbase * 1024 + d;
    const float* BCp = BC + rowbase * 32;

    float st[16] = {};
    float se[16] = {};

    for (int t = 0; t < SEGLEN; t++) {
        float dtv = dtp[(size_t)t * 2048];
        float u   = bf2f(up[(size_t)t * 1024]);
        float Bv[16];
        #pragma unroll
        for (int n = 0; n < 4; n++)
            *(float4*)&Bv[n * 4] = ((const float4*)(BCp + (size_t)t * 32))[n];
        float du = dtv * u;
        #pragma unroll
        for (int n = 0; n < 16; n++) {
            float e = clamp3(dtv * A2[n], -CL, CL);
            se[n] += e;
            st[n] = fast_exp2(e) * st[n] + du * Bv[n];
        }
    }

    size_t o = (((size_t)b * NSEG + seg) * 1024 + d) * 16;
    #pragma unroll
    for (int n = 0; n < 16; n++) {
        stA[o + n] = st[n];
        prA[o + n] = fast_exp2(clamp3(se[n], -115.41f, 115.41f));
    }
}

// ---------------------------------------------------------------------------
// Phase B: sequential combine over NSEG segments; stIn written IN PLACE over
// stA (read-before-write makes aliasing safe). Parallel over (b,d,n).
// ---------------------------------------------------------------------------
__global__ __launch_bounds__(256) void scan_combine(
    float* __restrict__ stA, const float* __restrict__ prA, int total)
{
    int idx = blockIdx.x * 256 + threadIdx.x;
    if (idx >= total) return;
    int dn = idx & 16383;           // d*16 + n
    int b  = idx >> 14;
    float prev = 0.f;
    for (int s = 0; s < NSEG; s++) {
        size_t o = ((size_t)b * NSEG + s) * 16384 + dn;
        float a = stA[o], pr = prA[o];
        stA[o] = prev;              // becomes stIn[seg]
        prev = a + pr * prev;       // garbage for s==NSEG-1, discarded
    }
}

// ---------------------------------------------------------------------------
// Phase C: re-run each segment with correct initial state (stIn aliased in
// stA); emit gated output y_bf = bf16((scan + u*D) * silu(res)).
// ---------------------------------------------------------------------------
__global__ __launch_bounds__(64) void scan_phaseC(
    const float* __restrict__ xres, const float* __restrict__ BC,
    const unsigned short* __restrict__ xc, const float* __restrict__ A_log,
    const float* __restrict__ Dvec, const float* __restrict__ stIn,
    unsigned short* __restrict__ y_bf)
{
    const int bx = blockIdx.x;
    const int seg = bx & (NSEG - 1);
    const int dg  = (bx >> 5) & 15;
    const int b   = bx >> 9;
    const int lane = threadIdx.x;
    const int d = dg * 64 + lane;
    const float CL = 5.f * LOG2E;

    float A2[16];
    #pragma unroll
    for (int n = 0; n < 16; n++) A2[n] = A_log[n] * LOG2E;
    const float Dp = Dvec[d];

    const size_t rowbase = (size_t)b * SEQ + (size_t)seg * SEGLEN;
    const float* dtp  = xres + rowbase * 2048 + d;
    const float* resp = xres + rowbase * 2048 + 1024 + d;
    const unsigned short* up = xc + rowbase * 1024 + d;
    const float* BCp = BC + rowbase * 32;
    unsigned short* yp = y_bf + rowbase * 1024 + d;

    float st[16];
    size_t o = (((size_t)b * NSEG + seg) * 1024 + d) * 16;
    #pragma unroll
    for (int n = 0; n < 16; n++) st[n] = stIn[o + n];

    for (int t = 0; t < SEGLEN; t++) {
        float dtv = dtp[(size_t)t * 2048];
        float u   = bf2f(up[(size_t)t * 1024]);
        float Bv[16], Cv[16];
        #pragma unroll
        for (int n = 0; n < 4; n++) {
            *(float4*)&Bv[n * 4] = ((const float4*)(BCp + (size_t)t * 32))[n];
            *(float4*)&Cv[n * 4] = ((const float4*)(BCp + (size_t)t * 32))[n + 4];
        }
        float du = dtv * u;
        float y = 0.f;
        #pragma unroll
        for (int n = 0; n < 16; n++) {
            float e = clamp3(dtv * A2[n], -CL, CL);
            st[n] = fast_exp2(e) * st[n] + du * Bv[n];
            y += st[n] * Cv[n];
        }
        float r = resp[(size_t)t * 2048];
        float outv = (y + u * Dp) * silu(r);
        yp[(size_t)t * 1024] = f2bf(outv);
    }
}

// ---------------------------------------------------------------------------
// LayerNorm over last dim (512), eps 1e-5, in-place.
// ---------------------------------------------------------------------------
__global__ __launch_bounds__(128) void ln_kernel(
    float* __restrict__ out, const float* __restrict__ g,
    const float* __restrict__ bta)
{
    const int row = blockIdx.x;
    float* p = out + (size_t)row * D_MODEL;
    const int tid = threadIdx.x;

    float4 v = ((const float4*)p)[tid];
    float s1 = v.x + v.y + v.z + v.w;
    float s2 = v.x * v.x + v.y * v.y + v.z * v.z + v.w * v.w;
    #pragma unroll
    for (int off = 32; off > 0; off >>= 1) {
        s1 += __shfl_xor(s1, off);
        s2 += __shfl_xor(s2, off);
    }
    __shared__ float r1[2], r2[2];
    if ((tid & 63) == 0) { r1[tid >> 6] = s1; r2[tid >> 6] = s2; }
    __syncthreads();
    s1 = r1[0] + r1[1];
    s2 = r2[0] + r2[1];

    const float mu  = s1 * (1.f / D_MODEL);
    const float var = s2 * (1.f / D_MODEL) - mu * mu;
    const float rstd = rsqrtf(var + 1e-5f);

    float4 gg = ((const float4*)g)[tid];
    float4 bb = ((const float4*)bta)[tid];
    float4 o;
    o.x = (v.x - mu) * rstd * gg.x + bb.x;
    o.y = (v.y - mu) * rstd * gg.y + bb.y;
    o.z = (v.z - mu) * rstd * gg.z + bb.z;
    o.w = (v.w - mu) * rstd * gg.w + bb.w;
    ((float4*)p)[tid] = o;
}

// ---------------------------------------------------------------------------
extern "C" void kernel_launch(void* const* d_in, const int* in_sizes, int n_in,
                              void* d_out, int out_size, void* d_ws, size_t ws_size,
                              hipStream_t stream)
{
    const float* x      = (const float*)d_in[0];
    const float* W_in   = (const float*)d_in[1];
    const float* conv_w = (const float*)d_in[2];
    const float* conv_b = (const float*)d_in[3];
    const float* W_x    = (const float*)d_in[4];
    const float* W_dt   = (const float*)d_in[5];
    const float* b_dt   = (const float*)d_in[6];
    const float* A_log  = (const float*)d_in[7];
    const float* Dv     = (const float*)d_in[8];
    const float* W_out  = (const float*)d_in[9];
    const float* ln_g   = (const float*)d_in[10];
    const float* ln_b   = (const float*)d_in[11];
    float* out = (float*)d_out;

    // ---- fixed workspace: bf16 weights ----
    const size_t szWin  = (size_t)2048 * 512;
    const size_t szWdt  = (size_t)1024 * 1024;
    const size_t szWout = (size_t)512 * 1024;
    const size_t szWx   = (size_t)32 * 1024;
    char* p = (char*)d_ws;
    unsigned short* Wib  = (unsigned short*)p; p += szWin * 2;
    unsigned short* Wdtb = (unsigned short*)p; p += szWdt * 2;
    unsigned short* Wob  = (unsigned short*)p; p += szWout * 2;
    unsigned short* Wxb  = (unsigned short*)p; p += szWx * 2;
    const size_t fixed_bytes = (size_t)(p - (char*)d_ws);

    // per-batch activation bytes (x_bf aliased into y_bf; stIn aliased in stA)
    const size_t per_batch =
        (size_t)SEQ * 2048 * 4                  // xres f32 (x_p/dt | res)
      + (size_t)SEQ * 1024 * 2                  // ybuf bf16 (also x_bf)
      + (size_t)SEQ * 1024 * 2                  // xc_bf
      + (size_t)SEQ * 32 * 4                    // BC f32
      + (size_t)2 * NSEG * 1024 * 16 * 4;       // stA, prA
    int cb = 16;
    while (cb > 1 && fixed_bytes + (size_t)cb * per_batch > ws_size) cb >>= 1;
    const int Mc = cb * SEQ;

    float*          xres  = (float*)p;          p += (size_t)Mc * 2048 * 4;
    unsigned short* ybuf  = (unsigned short*)p; p += (size_t)Mc * 1024 * 2;
    unsigned short* x_bf  = ybuf;               // dead before ybuf is written
    unsigned short* xc_bf = (unsigned short*)p; p += (size_t)Mc * 1024 * 2;
    float*          BCb   = (float*)p;          p += (size_t)Mc * 32 * 4;
    float*          stA   = (float*)p;          p += (size_t)cb * NSEG * 16384 * 4;
    float*          prA   = (float*)p;

    // ---- cast weights to bf16 (every call; ~10 us) ----
    cast_bf16<<<(int)(szWin / 4 + 255) / 256, 256, 0, stream>>>((const float4*)W_in,  (ushort4*)Wib,  (int)(szWin / 4), 0);
    cast_bf16<<<(int)(szWdt / 4 + 255) / 256, 256, 0, stream>>>((const float4*)W_dt,  (ushort4*)Wdtb, (int)(szWdt / 4), 0);
    cast_bf16<<<(int)(szWout / 4 + 255) / 256, 256, 0, stream>>>((const float4*)W_out, (ushort4*)Wob, (int)(szWout / 4), 0);
    cast_bf16<<<(int)(szWx / 4 + 255) / 256, 256, 0, stream>>>((const float4*)W_x,   (ushort4*)Wxb,  (int)(szWx / 4), 0);

    for (int b0 = 0; b0 < B_SZ; b0 += cb) {
        const float* xk   = x   + (size_t)b0 * SEQ * D_MODEL;
        float*       outk = out + (size_t)b0 * SEQ * D_MODEL;

        // 0) x -> bf16 with clip (into ybuf-aliased region)
        cast_bf16<<<(Mc * 512 / 4) / 256, 256, 0, stream>>>(
            (const float4*)xk, (ushort4*)x_bf, Mc * 512 / 4, 1);

        // 1) xres = clip(x) @ W_in^T   -> f32 [Mc,2048]
        gemm_bf16<<<dim3(2048 / 128, Mc / 128), 256, 0, stream>>>(
            x_bf, Wib, xres, 512, 2048, nullptr, nullptr, 0, 0);

        // 2) xc_bf = silu(conv(x_p) + conv_b)
        conv_silu<<<Mc, 256, 0, stream>>>(xres, conv_w, conv_b, xc_bf);

        // 3) BC = xc @ W_x^T  -> f32 [Mc,32]  (skinny MFMA, waves independent)
        gemm_bc<<<Mc / 64, 256, 0, stream>>>(xc_bf, Wxb, BCb);

        // 4) dt = xc @ W_dt^T + b_dt -> xres[:,0:1024] (ldc=2048)
        gemm_bf16<<<dim3(1024 / 128, Mc / 128), 256, 0, stream>>>(
            xc_bf, Wdtb, xres, 1024, 2048, b_dt, nullptr, 0, 0);

        // 5) segmented scan (A: partials; B: combine in place; C: emit y)
        scan_phaseA<<<cb * NSEG * 16, 64, 0, stream>>>(xres, BCb, xc_bf, A_log, stA, prA);
        scan_combine<<<(cb * 16384 + 255) / 256, 256, 0, stream>>>(stA, prA, cb * 16384);
        scan_phaseC<<<cb * NSEG * 16, 64, 0, stream>>>(xres, BCb, xc_bf, A_log, Dv, stA, ybuf);

        // 6) out = y @ W_out^T + clip(x)   -> [Mc,512]
        gemm_bf16<<<dim3(512 / 128, Mc / 128), 256, 0, stream>>>(
            ybuf, Wob, outk, 1024, 512, nullptr, xk, 512, 1);

        // 7) LayerNorm in-place
        ln_kernel<<<Mc, 128, 0, stream>>>(outk, ln_g, ln_b);
    }
}

// Round 6
// 981.790 us; speedup vs baseline: 7.4184x; 1.0316x over previous
//
#include <hip/hip_runtime.h>
#include <hip/hip_bf16.h>
#include <math.h>

#define B_SZ 16
#define SEQ 2048
#define D_MODEL 512
#define D_INNER 1024
#define D_STATE 16
#define D_CONV 4
#define NSEG 32
#define SEGLEN (SEQ / NSEG)   // 64
#define LOG2E 1.44269504f

typedef __attribute__((ext_vector_type(8))) short short8;
typedef __attribute__((ext_vector_type(4))) float f32x4;
typedef const __attribute__((address_space(1))) void* gas_ptr;
typedef __attribute__((address_space(3))) void* las_ptr;

__device__ __forceinline__ float bf2f(unsigned int bits16) {
    union { unsigned int i; float f; } v; v.i = bits16 << 16; return v.f;
}
__device__ __forceinline__ unsigned short f2bf(float f) {
    union { float f; unsigned int i; } v; v.f = f;
    unsigned int r = v.i + 0x7FFFu + ((v.i >> 16) & 1u);
    return (unsigned short)(r >> 16);
}
__device__ __forceinline__ void async_g2l(const void* g, void* l) {
    __builtin_amdgcn_global_load_lds((gas_ptr)g, (las_ptr)l, 16, 0, 0);
}
__device__ __forceinline__ float fast_exp2(float x) { return __builtin_amdgcn_exp2f(x); }
__device__ __forceinline__ float fast_rcp(float x)  { return __builtin_amdgcn_rcpf(x); }
__device__ __forceinline__ float clamp3(float x, float lo, float hi) {
    return __builtin_amdgcn_fmed3f(x, lo, hi);
}
__device__ __forceinline__ float silu(float x) {
    return x * fast_rcp(1.f + fast_exp2(-x * LOG2E));
}

// ---------------------------------------------------------------------------
// f32 -> bf16 cast (4 elements/thread), optional clip to [-10,10]
// ---------------------------------------------------------------------------
__global__ __launch_bounds__(256) void cast_bf16(
    const float4* __restrict__ in, ushort4* __restrict__ out, int n4, int do_clip)
{
    int i = blockIdx.x * 256 + threadIdx.x;
    if (i >= n4) return;
    float4 v = in[i];
    if (do_clip) {
        v.x = clamp3(v.x, -10.f, 10.f);
        v.y = clamp3(v.y, -10.f, 10.f);
        v.z = clamp3(v.z, -10.f, 10.f);
        v.w = clamp3(v.w, -10.f, 10.f);
    }
    ushort4 o;
    o.x = f2bf(v.x); o.y = f2bf(v.y); o.z = f2bf(v.z); o.w = f2bf(v.w);
    out[i] = o;
}

// ---------------------------------------------------------------------------
// bf16 MFMA NT-GEMM: C[M,N] = A[M,K] @ Bw[N,K]^T, 128x128 tile, BK=32,
// 4 waves (2x2 of 64x64), 16x16x32 bf16 MFMA.
// 1-D grid with XCD-aware swizzle: block h -> xcd k=h&7 owns row-blocks
// {k, k+8, ...} across all column-blocks, so each A-tile is fetched by one
// XCD's L2 only. nbn_shift = log2(N/128). Requires (M/128) % 8 == 0.
// LDS uses XOR-swizzled 16B slots: chunk g of row R sits at slot
// (g + (R>>1)) & 3 -> read bank-group (4R + q + (R>>1)) % 8 is a perfect
// permutation -> 2-way (free) instead of 8-way conflicts.
// f32 epilogue: +bias[n], +add[m,n] (optionally clipped to +-10).
// ---------------------------------------------------------------------------
__global__ __launch_bounds__(256) void gemm_bf16(
    const unsigned short* __restrict__ A, const unsigned short* __restrict__ Bw,
    float* __restrict__ C, int K, int ldc, int nbn_shift,
    const float* __restrict__ bias,
    const float* __restrict__ add, int ldadd, int clip_add)
{
    __shared__ unsigned short As[128][32];
    __shared__ unsigned short Bs[128][32];
    const int h = blockIdx.x;
    const int xk = h & 7;
    const int qb = h >> 3;
    const int bn = (qb & ((1 << nbn_shift) - 1)) * 128;
    const int bm = ((qb >> nbn_shift) * 8 + xk) * 128;
    const int tid = threadIdx.x;
    const int wv = tid >> 6;
    const int l  = tid & 63;
    const int lr = l >> 2;            // staging row within 16-row chunk
    const int lc = l & 3;             // staging slot (fixed by lane)
    const int wm = (wv >> 1) * 64;
    const int wn = (wv & 1) * 64;
    const int r16 = l & 15;
    const int q   = l >> 4;
    // staging: global chunk that must land in slot lc for row lr
    const int gsw = (lc - ((lr >> 1) & 3)) & 3;
    // reading: slot holding global chunk q for row r16
    const int ssw = ((q + ((r16 >> 1) & 3)) & 3) * 8;

    f32x4 acc[4][4];
    #pragma unroll
    for (int i = 0; i < 4; i++)
        #pragma unroll
        for (int j = 0; j < 4; j++)
            acc[i][j] = (f32x4){0.f, 0.f, 0.f, 0.f};

    for (int k0 = 0; k0 < K; k0 += 32) {
        #pragma unroll
        for (int p = 0; p < 2; p++) {
            int row = wv * 32 + p * 16 + lr;
            async_g2l((const char*)A + (((size_t)(bm + row)) * K + k0 + gsw * 8) * 2,
                      (char*)&As[0][0] + (wv * 32 + p * 16) * 64);
            async_g2l((const char*)Bw + (((size_t)(bn + row)) * K + k0 + gsw * 8) * 2,
                      (char*)&Bs[0][0] + (wv * 32 + p * 16) * 64);
        }
        __syncthreads();

        short8 af[4], bf[4];
        #pragma unroll
        for (int i = 0; i < 4; i++) {
            af[i] = *(const short8*)&As[wm + i * 16 + r16][ssw];
            bf[i] = *(const short8*)&Bs[wn + i * 16 + r16][ssw];
        }
        #pragma unroll
        for (int i = 0; i < 4; i++)
            #pragma unroll
            for (int j = 0; j < 4; j++)
                acc[i][j] = __builtin_amdgcn_mfma_f32_16x16x32_bf16(
                    af[i], bf[j], acc[i][j], 0, 0, 0);
        __syncthreads();
    }

    #pragma unroll
    for (int i = 0; i < 4; i++) {
        #pragma unroll
        for (int rr = 0; rr < 4; rr++) {
            int m = bm + wm + i * 16 + q * 4 + rr;
            #pragma unroll
            for (int j = 0; j < 4; j++) {
                int n = bn + wn + j * 16 + r16;
                float v = acc[i][j][rr];
                if (bias) v += bias[n];
                if (add) {
                    float a = add[(size_t)m * ldadd + n];
                    if (clip_add) a = clamp3(a, -10.f, 10.f);
                    v += a;
                }
                C[(size_t)m * ldc + n] = v;
            }
        }
    }
}

// ---------------------------------------------------------------------------
// Skinny MFMA GEMM: BC[rows,32] = xc_bf[rows,1024] @ W_x_bf[32,1024]^T.
// One wave per 16 output rows; no LDS, no barriers.
// ---------------------------------------------------------------------------
__global__ __launch_bounds__(256) void gemm_bc(
    const unsigned short* __restrict__ A, const unsigned short* __restrict__ Bw,
    float* __restrict__ C)
{
    const int tid = threadIdx.x;
    const int wv  = tid >> 6;
    const int l   = tid & 63;
    const int r16 = l & 15;
    const int q   = l >> 4;
    const int row0 = blockIdx.x * 64 + wv * 16;

    const unsigned short* ap  = A  + (size_t)(row0 + r16) * 1024 + q * 8;
    const unsigned short* bp0 = Bw + (size_t)r16 * 1024 + q * 8;
    const unsigned short* bp1 = Bw + (size_t)(16 + r16) * 1024 + q * 8;

    f32x4 acc0 = {0.f, 0.f, 0.f, 0.f}, acc1 = {0.f, 0.f, 0.f, 0.f};
    #pragma unroll 4
    for (int k = 0; k < 1024; k += 32) {
        short8 af = *(const short8*)(ap + k);
        short8 b0 = *(const short8*)(bp0 + k);
        short8 b1 = *(const short8*)(bp1 + k);
        acc0 = __builtin_amdgcn_mfma_f32_16x16x32_bf16(af, b0, acc0, 0, 0, 0);
        acc1 = __builtin_amdgcn_mfma_f32_16x16x32_bf16(af, b1, acc1, 0, 0, 0);
    }
    #pragma unroll
    for (int rr = 0; rr < 4; rr++) {
        int m = row0 + q * 4 + rr;
        C[(size_t)m * 32 + r16]      = acc0[rr];
        C[(size_t)m * 32 + 16 + r16] = acc1[rr];
    }
}

// ---------------------------------------------------------------------------
// Depthwise causal conv (width 4) + bias + SiLU; 4 channels/thread (float4).
// ---------------------------------------------------------------------------
__global__ __launch_bounds__(256) void conv_silu(
    const float* __restrict__ xres, const float* __restrict__ cw,
    const float* __restrict__ cb, unsigned short* __restrict__ xc)
{
    int idx = blockIdx.x * 256 + threadIdx.x;
    int c4 = (idx & 255) << 2;
    int bt = idx >> 8;
    int t  = bt & (SEQ - 1);

    float4 acc = *(const float4*)(cb + c4);
    float4 w0 = *(const float4*)(cw + (c4 + 0) * 4);
    float4 w1 = *(const float4*)(cw + (c4 + 1) * 4);
    float4 w2 = *(const float4*)(cw + (c4 + 2) * 4);
    float4 w3 = *(const float4*)(cw + (c4 + 3) * 4);

    #pragma unroll
    for (int k = 0; k < D_CONV; k++) {
        int tt = t - (D_CONV - 1) + k;
        if (tt >= 0) {
            float4 xv = *(const float4*)(xres + (size_t)(bt - (D_CONV - 1) + k) * 2048 + c4);
            acc.x += xv.x * ((const float*)&w0)[k];
            acc.y += xv.y * ((const float*)&w1)[k];
            acc.z += xv.z * ((const float*)&w2)[k];
            acc.w += xv.w * ((const float*)&w3)[k];
        }
    }
    ushort4 o;
    o.x = f2bf(silu(acc.x));
    o.y = f2bf(silu(acc.y));
    o.z = f2bf(silu(acc.z));
    o.w = f2bf(silu(acc.w));
    *(ushort4*)(xc + (size_t)bt * 1024 + c4) = o;
}

// ---------------------------------------------------------------------------
// Segmented scan phase A.
// ---------------------------------------------------------------------------
__global__ __launch_bounds__(64) void scan_phaseA(
    const float* __restrict__ xres, const float* __restrict__ BC,
    const unsigned short* __restrict__ xc, const float* __restrict__ A_log,
    float* __restrict__ stA, float* __restrict__ prA)
{
    const int bx = blockIdx.x;
    const int seg = bx & (NSEG - 1);
    const int dg  = (bx >> 5) & 15;
    const int b   = bx >> 9;
    if (seg == NSEG - 1) return;
    const int lane = threadIdx.x;
    const int d = dg * 64 + lane;
    const float CL = 5.f * LOG2E;

    float A2[16];
    #pragma unroll
    for (int n = 0; n < 16; n++) A2[n] = A_log[n] * LOG2E;

    const size_t rowbase = (size_t)b * SEQ + (size_t)seg * SEGLEN;
    const float* dtp = xres + rowbase * 2048 + d;
    const unsigned short* up = xc + rowbase * 1024 + d;
    const float* BCp = BC + rowbase * 32;

    float st[16] = {};
    float se[16] = {};

    for (int t = 0; t < SEGLEN; t++) {
        float dtv = dtp[(size_t)t * 2048];
        float u   = bf2f(up[(size_t)t * 1024]);
        float Bv[16];
        #pragma unroll
        for (int n = 0; n < 4; n++)
            *(float4*)&Bv[n * 4] = ((const float4*)(BCp + (size_t)t * 32))[n];
        float du = dtv * u;
        #pragma unroll
        for (int n = 0; n < 16; n++) {
            float e = clamp3(dtv * A2[n], -CL, CL);
            se[n] += e;
            st[n] = fast_exp2(e) * st[n] + du * Bv[n];
        }
    }

    size_t o = (((size_t)b * NSEG + seg) * 1024 + d) * 16;
    #pragma unroll
    for (int n = 0; n < 16; n++) {
        stA[o + n] = st[n];
        prA[o + n] = fast_exp2(clamp3(se[n], -115.41f, 115.41f));
    }
}

// ---------------------------------------------------------------------------
// Phase B: sequential combine; stIn written in place over stA.
// ---------------------------------------------------------------------------
__global__ __launch_bounds__(256) void scan_combine(
    float* __restrict__ stA, const float* __restrict__ prA, int total)
{
    int idx = blockIdx.x * 256 + threadIdx.x;
    if (idx >= total) return;
    int dn = idx & 16383;
    int b  = idx >> 14;
    float prev = 0.f;
    for (int s = 0; s < NSEG; s++) {
        size_t o = ((size_t)b * NSEG + s) * 16384 + dn;
        float a = stA[o], pr = prA[o];
        stA[o] = prev;
        prev = a + pr * prev;
    }
}

// ---------------------------------------------------------------------------
// Phase C: re-run segments with correct init; emit gated output.
// ---------------------------------------------------------------------------
__global__ __launch_bounds__(64) void scan_phaseC(
    const float* __restrict__ xres, const float* __restrict__ BC,
    const unsigned short* __restrict__ xc, const float* __restrict__ A_log,
    const float* __restrict__ Dvec, const float* __restrict__ stIn,
    unsigned short* __restrict__ y_bf)
{
    const int bx = blockIdx.x;
    const int seg = bx & (NSEG - 1);
    const int dg  = (bx >> 5) & 15;
    const int b   = bx >> 9;
    const int lane = threadIdx.x;
    const int d = dg * 64 + lane;
    const float CL = 5.f * LOG2E;

    float A2[16];
    #pragma unroll
    for (int n = 0; n < 16; n++) A2[n] = A_log[n] * LOG2E;
    const float Dp = Dvec[d];

    const size_t rowbase = (size_t)b * SEQ + (size_t)seg * SEGLEN;
    const float* dtp  = xres + rowbase * 2048 + d;
    const float* resp = xres + rowbase * 2048 + 1024 + d;
    const unsigned short* up = xc + rowbase * 1024 + d;
    const float* BCp = BC + rowbase * 32;
    unsigned short* yp = y_bf + rowbase * 1024 + d;

    float st[16];
    size_t o = (((size_t)b * NSEG + seg) * 1024 + d) * 16;
    #pragma unroll
    for (int n = 0; n < 16; n++) st[n] = stIn[o + n];

    for (int t = 0; t < SEGLEN; t++) {
        float dtv = dtp[(size_t)t * 2048];
        float u   = bf2f(up[(size_t)t * 1024]);
        float Bv[16], Cv[16];
        #pragma unroll
        for (int n = 0; n < 4; n++) {
            *(float4*)&Bv[n * 4] = ((const float4*)(BCp + (size_t)t * 32))[n];
            *(float4*)&Cv[n * 4] = ((const float4*)(BCp + (size_t)t * 32))[n + 4];
        }
        float du = dtv * u;
        float y = 0.f;
        #pragma unroll
        for (int n = 0; n < 16; n++) {
            float e = clamp3(dtv * A2[n], -CL, CL);
            st[n] = fast_exp2(e) * st[n] + du * Bv[n];
            y += st[n] * Cv[n];
        }
        float r = resp[(size_t)t * 2048];
        float outv = (y + u * Dp) * silu(r);
        yp[(size_t)t * 1024] = f2bf(outv);
    }
}

// ---------------------------------------------------------------------------
// LayerNorm over last dim (512), eps 1e-5, in-place.
// ---------------------------------------------------------------------------
__global__ __launch_bounds__(128) void ln_kernel(
    float* __restrict__ out, const float* __restrict__ g,
    const float* __restrict__ bta)
{
    const int row = blockIdx.x;
    float* p = out + (size_t)row * D_MODEL;
    const int tid = threadIdx.x;

    float4 v = ((const float4*)p)[tid];
    float s1 = v.x + v.y + v.z + v.w;
    float s2 = v.x * v.x + v.y * v.y + v.z * v.z + v.w * v.w;
    #pragma unroll
    for (int off = 32; off > 0; off >>= 1) {
        s1 += __shfl_xor(s1, off);
        s2 += __shfl_xor(s2, off);
    }
    __shared__ float r1[2], r2[2];
    if ((tid & 63) == 0) { r1[tid >> 6] = s1; r2[tid >> 6] = s2; }
    __syncthreads();
    s1 = r1[0] + r1[1];
    s2 = r2[0] + r2[1];

    const float mu  = s1 * (1.f / D_MODEL);
    const float var = s2 * (1.f / D_MODEL) - mu * mu;
    const float rstd = rsqrtf(var + 1e-5f);

    float4 gg = ((const float4*)g)[tid];
    float4 bb = ((const float4*)bta)[tid];
    float4 o;
    o.x = (v.x - mu) * rstd * gg.x + bb.x;
    o.y = (v.y - mu) * rstd * gg.y + bb.y;
    o.z = (v.z - mu) * rstd * gg.z + bb.z;
    o.w = (v.w - mu) * rstd * gg.w + bb.w;
    ((float4*)p)[tid] = o;
}

// ---------------------------------------------------------------------------
extern "C" void kernel_launch(void* const* d_in, const int* in_sizes, int n_in,
                              void* d_out, int out_size, void* d_ws, size_t ws_size,
                              hipStream_t stream)
{
    const float* x      = (const float*)d_in[0];
    const float* W_in   = (const float*)d_in[1];
    const float* conv_w = (const float*)d_in[2];
    const float* conv_b = (const float*)d_in[3];
    const float* W_x    = (const float*)d_in[4];
    const float* W_dt   = (const float*)d_in[5];
    const float* b_dt   = (const float*)d_in[6];
    const float* A_log  = (const float*)d_in[7];
    const float* Dv     = (const float*)d_in[8];
    const float* W_out  = (const float*)d_in[9];
    const float* ln_g   = (const float*)d_in[10];
    const float* ln_b   = (const float*)d_in[11];
    float* out = (float*)d_out;

    // ---- fixed workspace: bf16 weights ----
    const size_t szWin  = (size_t)2048 * 512;
    const size_t szWdt  = (size_t)1024 * 1024;
    const size_t szWout = (size_t)512 * 1024;
    const size_t szWx   = (size_t)32 * 1024;
    char* p = (char*)d_ws;
    unsigned short* Wib  = (unsigned short*)p; p += szWin * 2;
    unsigned short* Wdtb = (unsigned short*)p; p += szWdt * 2;
    unsigned short* Wob  = (unsigned short*)p; p += szWout * 2;
    unsigned short* Wxb  = (unsigned short*)p; p += szWx * 2;
    const size_t fixed_bytes = (size_t)(p - (char*)d_ws);

    const size_t per_batch =
        (size_t)SEQ * 2048 * 4
      + (size_t)SEQ * 1024 * 2
      + (size_t)SEQ * 1024 * 2
      + (size_t)SEQ * 32 * 4
      + (size_t)2 * NSEG * 1024 * 16 * 4;
    int cb = 16;
    while (cb > 1 && fixed_bytes + (size_t)cb * per_batch > ws_size) cb >>= 1;
    const int Mc = cb * SEQ;

    float*          xres  = (float*)p;          p += (size_t)Mc * 2048 * 4;
    unsigned short* ybuf  = (unsigned short*)p; p += (size_t)Mc * 1024 * 2;
    unsigned short* x_bf  = ybuf;               // dead before ybuf is written
    unsigned short* xc_bf = (unsigned short*)p; p += (size_t)Mc * 1024 * 2;
    float*          BCb   = (float*)p;          p += (size_t)Mc * 32 * 4;
    float*          stA   = (float*)p;          p += (size_t)cb * NSEG * 16384 * 4;
    float*          prA   = (float*)p;

    cast_bf16<<<(int)(szWin / 4 + 255) / 256, 256, 0, stream>>>((const float4*)W_in,  (ushort4*)Wib,  (int)(szWin / 4), 0);
    cast_bf16<<<(int)(szWdt / 4 + 255) / 256, 256, 0, stream>>>((const float4*)W_dt,  (ushort4*)Wdtb, (int)(szWdt / 4), 0);
    cast_bf16<<<(int)(szWout / 4 + 255) / 256, 256, 0, stream>>>((const float4*)W_out, (ushort4*)Wob, (int)(szWout / 4), 0);
    cast_bf16<<<(int)(szWx / 4 + 255) / 256, 256, 0, stream>>>((const float4*)W_x,   (ushort4*)Wxb,  (int)(szWx / 4), 0);

    for (int b0 = 0; b0 < B_SZ; b0 += cb) {
        const float* xk   = x   + (size_t)b0 * SEQ * D_MODEL;
        float*       outk = out + (size_t)b0 * SEQ * D_MODEL;

        // 0) x -> bf16 with clip
        cast_bf16<<<(Mc * 512 / 4) / 256, 256, 0, stream>>>(
            (const float4*)xk, (ushort4*)x_bf, Mc * 512 / 4, 1);

        // 1) xres = clip(x) @ W_in^T   (N=2048 -> nbn_shift=4)
        gemm_bf16<<<(2048 / 128) * (Mc / 128), 256, 0, stream>>>(
            x_bf, Wib, xres, 512, 2048, 4, nullptr, nullptr, 0, 0);

        // 2) xc_bf = silu(conv(x_p) + conv_b)
        conv_silu<<<Mc, 256, 0, stream>>>(xres, conv_w, conv_b, xc_bf);

        // 3) BC = xc @ W_x^T
        gemm_bc<<<Mc / 64, 256, 0, stream>>>(xc_bf, Wxb, BCb);

        // 4) dt = xc @ W_dt^T + b_dt -> xres[:,0:1024]  (N=1024 -> shift=3)
        gemm_bf16<<<(1024 / 128) * (Mc / 128), 256, 0, stream>>>(
            xc_bf, Wdtb, xres, 1024, 2048, 3, b_dt, nullptr, 0, 0);

        // 5) segmented scan
        scan_phaseA<<<cb * NSEG * 16, 64, 0, stream>>>(xres, BCb, xc_bf, A_log, stA, prA);
        scan_combine<<<(cb * 16384 + 255) / 256, 256, 0, stream>>>(stA, prA, cb * 16384);
        scan_phaseC<<<cb * NSEG * 16, 64, 0, stream>>>(xres, BCb, xc_bf, A_log, Dv, stA, ybuf);

        // 6) out = y @ W_out^T + clip(x)   (N=512 -> shift=2)
        gemm_bf16<<<(512 / 128) * (Mc / 128), 256, 0, stream>>>(
            ybuf, Wob, outk, 1024, 512, 2, nullptr, xk, 512, 1);

        // 7) LayerNorm in-place
        ln_kernel<<<Mc, 128, 0, stream>>>(outk, ln_g, ln_b);
    }
}